// Round 13
// baseline (131.100 us; speedup 1.0000x reference)
//
#include <hip/hip_runtime.h>
#include <utility>

#define NW 14
#define NL 3
#define DIM 16384            // 2^14
#define NG  (NL * NW)        // 42 fused RY*RX gates
#define TPB 1024
#define NPH3 11              // 10 phases of 4 gates + 1 phase of 2

typedef float v2f __attribute__((ext_vector_type(2)));

struct S3 {
    int ok = 1;
    unsigned Lane[NPH3][6] = {};   // lane dirs (tid bits 0..5) per phase
    unsigned Reg[NPH3][4]  = {};   // register/slot dirs per phase
    unsigned Vw[4]         = {};   // global wave dirs (tid bits 6..9)
    unsigned WT[NPH3][6]   = {};   // write consts: coords of lane dirs in NEXT frame
    unsigned WS[NPH3][16]  = {};   // write consts: coords of slot XORs in NEXT frame
    unsigned pv[NPH3][4]   = {};   // runtime sign: 10-bit tid parity mask per gate
    unsigned cp[NPH3][4]   = {};   // compile-time per-slot role bits per gate
    unsigned ST[10] = {}, STK[4] = {}, STJ[4] = {};   // staging coords (phase-0 frame)
    unsigned pz[NW] = {}, nib[NW] = {};               // measurement maps
};

// ---- cheap incremental echelon (no coords) ----
struct Bas14 { unsigned piv[14] = {}; int n = 0; };
constexpr bool binsert(Bas14& B, unsigned v) {
    unsigned x = v;
    for (int bit = 13; bit >= 0; --bit) {
        if (!((x >> bit) & 1u)) continue;
        if (B.piv[bit]) x ^= B.piv[bit];
        else { B.piv[bit] = x; ++B.n; return true; }
    }
    return false;
}

// ---- echelon with coordinate tracking: built ONCE per basis, cheap solves ----
struct Ech { unsigned pv14[14] = {}; unsigned pc14[14] = {}; int ok = 1; };
constexpr Ech mkech(const unsigned bas[14]) {
    Ech E{};
    for (int b = 0; b < 14; ++b) {
        unsigned x = bas[b], c = 1u << b;
        for (int bit = 13; bit >= 0; --bit) {
            if (!((x >> bit) & 1u)) continue;
            if (E.pv14[bit]) { x ^= E.pv14[bit]; c ^= E.pc14[bit]; }
            else { E.pv14[bit] = x; E.pc14[bit] = c; x = 0; break; }
        }
        if (x) E.ok = 0;
    }
    return E;
}
constexpr unsigned coordsE(const Ech& E, unsigned v, int& ok) {
    unsigned x = v, c = 0;
    for (int bit = 13; bit >= 0; --bit) {
        if ((x >> bit) & 1u) {
            if (!E.pv14[bit]) { ok = 0; return 0; }
            x ^= E.pv14[bit]; c ^= E.pc14[bit];
        }
    }
    return c;
}

constexpr S3 build3(int vskip) {
    S3 S{};
    unsigned mk[NG] = {}, vmg[NG] = {}, zm[NW] = {};
    {
        unsigned A[NW] = {};
        for (int w = 0; w < NW; ++w) A[w] = 1u << (NW - 1 - w);
        int g = 0;
        for (int l = 0; l < NL; ++l) {
            unsigned rows[NW] = {};
            for (int u = 0; u < NW; ++u) rows[u] = A[u] | (1u << (NW + u));
            for (int col = 0; col < NW; ++col) {
                int piv = col;
                while (piv < NW && !((rows[piv] >> col) & 1u)) ++piv;
                if (piv >= NW) { S.ok = 0; continue; }
                unsigned tmp = rows[col]; rows[col] = rows[piv]; rows[piv] = tmp;
                for (int r = 0; r < NW; ++r)
                    if (r != col && ((rows[r] >> col) & 1u)) rows[r] ^= rows[col];
            }
            for (int w = 0; w < NW; ++w) {
                unsigned m = 0;
                for (int r = 0; r < NW; ++r) m |= ((rows[r] >> (NW + w)) & 1u) << r;
                mk[g] = m; vmg[g] = A[w]; ++g;
            }
            for (int w = 0; w < NW - 1; ++w) A[w + 1] ^= A[w];  // virtual CNOT chain
            A[0] ^= A[NW - 1];
        }
        for (int w = 0; w < NW; ++w) zm[w] = A[w];
    }
    for (int p = 0; p < NPH3; ++p) {
        int J = (p < 10) ? 4 : 2;
        for (int q = 0; q < J; ++q) S.Reg[p][q] = mk[4 * p + q];
    }
    // global wave dirs: random 4-dim subspace independent of every group span
    {
        Bas14 gb[6] = {};
        for (int g = 0; g < 6; ++g) {
            int nm = (g < 5) ? 8 : 2;
            for (int i = 0; i < nm; ++i) binsert(gb[g], mk[8 * g + i]);
        }
        int found = 0, skipped = 0;
        for (unsigned seed = 1; seed < 512u && !found; ++seed) {
            unsigned cand[4] = {};
            for (int i = 0; i < 4; ++i) {
                unsigned h = (seed * 2654435761u) ^ ((unsigned)(i + 1) * 0x9E3779B9u);
                h ^= h >> 15; h *= 2246822519u; h ^= h >> 13; h *= 3266489917u; h ^= h >> 16;
                cand[i] = h & 0x3FFFu;
            }
            Bas14 cb{};
            bool good = binsert(cb, cand[0]) && binsert(cb, cand[1])
                     && binsert(cb, cand[2]) && binsert(cb, cand[3]);
            for (int g = 0; g < 6 && good; ++g) {
                Bas14 t = gb[g];
                for (int i = 0; i < 4 && good; ++i)
                    if (!binsert(t, cand[i])) good = false;
            }
            if (good) {
                if (skipped < vskip) { ++skipped; continue; }
                for (int i = 0; i < 4; ++i) S.Vw[i] = cand[i];
                found = 1;
            }
        }
        if (!found) S.ok = 0;
    }
    // per group: fillers and raw lane dirs (incremental echelon)
    for (int g = 0; g < 6; ++g) {
        int nm = (g < 5) ? 8 : 2;
        Bas14 B{};
        for (int i = 0; i < 4; ++i) binsert(B, S.Vw[i]);
        for (int i = 0; i < nm; ++i) binsert(B, mk[8 * g + i]);
        unsigned fill[12] = {}; int nf = 0;
        for (int b = 0; b < 14 && B.n < 14; ++b)
            if (binsert(B, 1u << b)) fill[nf++] = 1u << b;
        if (B.n != 14) S.ok = 0;
        if (g < 5) {
            int pA = 2 * g, pB = 2 * g + 1;
            for (int b = 0; b < 4; ++b) { S.Lane[pA][b] = S.Reg[pB][b]; S.Lane[pB][b] = S.Reg[pA][b]; }
            S.Lane[pA][4] = fill[0]; S.Lane[pA][5] = fill[1];
            S.Lane[pB][4] = fill[0]; S.Lane[pB][5] = fill[1];
        } else {
            S.Reg[10][2] = fill[0]; S.Reg[10][3] = fill[1];
            for (int b = 0; b < 6; ++b) S.Lane[10][b] = fill[2 + b];
        }
    }
    // transitions in reverse (echelon built once per transition)
    for (int t = NPH3 - 2; t >= 0; --t) {
        unsigned bas[14] = {};
        for (int b = 0; b < 6; ++b) bas[b] = S.Lane[t + 1][b];
        for (int q = 0; q < 4; ++q) bas[6 + q] = S.Reg[t + 1][q];
        for (int j = 0; j < 4; ++j) bas[10 + j] = S.Vw[j];
        Ech E = mkech(bas);
        if (!E.ok) S.ok = 0;
        unsigned rb[4] = {}; int rn = 0;
        for (int b = 0; b < 6; ++b) {
            int bestcs = 0, bestg = -1; unsigned bestr = 0;
            for (int cs = 0; cs < 16; ++cs) {
                unsigned c = 0;
                for (int q = 0; q < 4; ++q) if ((cs >> q) & 1) c ^= S.Reg[t][q];
                int ok2 = 1;
                unsigned r = coordsE(E, S.Lane[t][b] ^ c, ok2) & 15u;
                if (!ok2) continue;
                unsigned x = r;
                for (int i = 0; i < rn; ++i) {
                    int hb = 3; while (hb > 0 && !((rb[i] >> hb) & 1u)) --hb;
                    if ((x >> hb) & 1u) x ^= rb[i];
                }
                int gain = x ? 1 : 0;
                if (gain > bestg) { bestg = gain; bestcs = cs; bestr = r; }
                if (gain == 1) break;
            }
            unsigned c = 0;
            for (int q = 0; q < 4; ++q) if ((bestcs >> q) & 1) c ^= S.Reg[t][q];
            S.Lane[t][b] ^= c;
            unsigned x = bestr;
            for (int i = 0; i < rn; ++i) {
                int hb = 3; while (hb > 0 && !((rb[i] >> hb) & 1u)) --hb;
                if ((x >> hb) & 1u) x ^= rb[i];
            }
            if (x && rn < 4) rb[rn++] = x;
        }
        int okc = 1;
        for (int b = 0; b < 6; ++b) S.WT[t][b] = coordsE(E, S.Lane[t][b], okc);
        for (int s = 0; s < 16; ++s) {
            unsigned v = 0;
            for (int q = 0; q < 4; ++q) if ((s >> q) & 1) v ^= S.Reg[t][q];
            S.WS[t][s] = coordsE(E, v, okc);
        }
        if (!okc) S.ok = 0;
        // verify: reader-amp(writer-idx) == writer-amp on basis inputs
        for (int ub = 0; ub < 10; ++ub) {
            unsigned wamp = (ub < 6) ? S.Lane[t][ub] : S.Vw[ub - 6];
            unsigned widx = (ub < 6) ? S.WT[t][ub] : (1u << (10 + ub - 6));
            unsigned ramp = 0;
            for (int b = 0; b < 6; ++b) if ((widx >> b) & 1u) ramp ^= S.Lane[t + 1][b];
            for (int q = 0; q < 4; ++q) if ((widx >> (6 + q)) & 1u) ramp ^= S.Reg[t + 1][q];
            for (int j = 0; j < 4; ++j) if ((widx >> (10 + j)) & 1u) ramp ^= S.Vw[j];
            if (ramp != wamp) S.ok = 0;
        }
        for (int q = 0; q < 4; ++q) {
            unsigned widx = S.WS[t][1u << q];
            unsigned ramp = 0;
            for (int b = 0; b < 6; ++b) if ((widx >> b) & 1u) ramp ^= S.Lane[t + 1][b];
            for (int qq = 0; qq < 4; ++qq) if ((widx >> (6 + qq)) & 1u) ramp ^= S.Reg[t + 1][qq];
            for (int j = 0; j < 4; ++j) if ((widx >> (10 + j)) & 1u) ramp ^= S.Vw[j];
            if (ramp != S.Reg[t][q]) S.ok = 0;
        }
    }
    // signs
    for (int p = 0; p < NPH3; ++p) {
        int J = (p < 10) ? 4 : 2;
        for (int q = 0; q < J; ++q) {
            unsigned vm = vmg[4 * p + q], pvm = 0;
            for (int b = 0; b < 6; ++b)
                if (__builtin_popcount(S.Lane[p][b] & vm) & 1) pvm |= 1u << b;
            for (int j = 0; j < 4; ++j)
                if (__builtin_popcount(S.Vw[j] & vm) & 1) pvm |= 1u << (6 + j);
            S.pv[p][q] = pvm;
            unsigned cpm = 0;
            for (int s = 0; s < 16; ++s) {
                unsigned v = 0;
                for (int q2 = 0; q2 < 4; ++q2) if ((s >> q2) & 1) v ^= S.Reg[p][q2];
                if (__builtin_popcount(v & vm) & 1) cpm |= 1u << s;
            }
            S.cp[p][q] = cpm;
        }
    }
    // staging coords + verification
    {
        unsigned bas[14] = {};
        for (int b = 0; b < 6; ++b) bas[b] = S.Lane[0][b];
        for (int q = 0; q < 4; ++q) bas[6 + q] = S.Reg[0][q];
        for (int j = 0; j < 4; ++j) bas[10 + j] = S.Vw[j];
        Ech E = mkech(bas);
        if (!E.ok) S.ok = 0;
        int okc = 1;
        for (int b = 0; b < 10; ++b) S.ST[b] = coordsE(E, 1u << (b + 2), okc);
        for (int k = 0; k < 4; ++k) S.STK[k] = coordsE(E, (unsigned)k << 12, okc);
        for (int j = 0; j < 4; ++j) S.STJ[j] = coordsE(E, (unsigned)j, okc);
        if (!okc) S.ok = 0;
        for (int ub = 0; ub < 18; ++ub) {
            unsigned amp = (ub < 10) ? (1u << (ub + 2))
                         : (ub < 14) ? ((unsigned)(ub - 10) << 12) : (unsigned)(ub - 14);
            unsigned widx = (ub < 10) ? S.ST[ub] : (ub < 14) ? S.STK[ub - 10] : S.STJ[ub - 14];
            unsigned ramp = 0;
            for (int b = 0; b < 6; ++b) if ((widx >> b) & 1u) ramp ^= S.Lane[0][b];
            for (int q = 0; q < 4; ++q) if ((widx >> (6 + q)) & 1u) ramp ^= S.Reg[0][q];
            for (int j = 0; j < 4; ++j) if ((widx >> (10 + j)) & 1u) ramp ^= S.Vw[j];
            if (ramp != amp) S.ok = 0;
        }
    }
    // measurement from phase-10 registers
    for (int w = 0; w < NW; ++w) {
        unsigned pzm = 0;
        for (int b = 0; b < 6; ++b)
            if (__builtin_popcount(S.Lane[10][b] & zm[w]) & 1) pzm |= 1u << b;
        for (int j = 0; j < 4; ++j)
            if (__builtin_popcount(S.Vw[j] & zm[w]) & 1) pzm |= 1u << (6 + j);
        S.pz[w] = pzm;
        unsigned nv = 0;
        for (int q = 0; q < 4; ++q)
            if (__builtin_popcount(S.Reg[10][q] & zm[w]) & 1) nv |= 1u << q;
        S.nib[w] = nv;
    }
    return S;
}
constexpr S3 pickBuild() {
    for (int v = 0; v < 4; ++v) {
        S3 s = build3(v);
        if (s.ok) return s;
    }
    S3 bad{}; bad.ok = 0; return bad;
}
constexpr S3 SC3 = pickBuild();
static_assert(SC3.ok == 1, "schedule build failed");

// ---------------- static_for ----------------
template<class F, unsigned... I>
__device__ __forceinline__ void static_for_impl(F&& f, std::integer_sequence<unsigned, I...>) {
    (f(std::integral_constant<unsigned, I>{}), ...);
}
template<unsigned N, class F>
__device__ __forceinline__ void static_for(F&& f) {
    static_for_impl(static_cast<F&&>(f), std::make_integer_sequence<unsigned, N>{});
}

// ---------------- packed complex mul/mac (verified r4..r12) ----------------
template<int NEGLO, int NEGHI>
__device__ __forceinline__ v2f cmul(v2f k, v2f x) {
    v2f y;
    if constexpr (!NEGLO)
        asm("v_pk_mul_f32 %0, %1, %2 op_sel:[0,0] op_sel_hi:[0,1]"
            : "=&v"(y) : "v"(k), "v"(x));
    else
        asm("v_pk_mul_f32 %0, %1, %2 op_sel:[0,0] op_sel_hi:[0,1] neg_lo:[1,0] neg_hi:[1,0]"
            : "=&v"(y) : "v"(k), "v"(x));
    if constexpr (!NEGHI)
        asm("v_pk_fma_f32 %0, %1, %2, %0 op_sel:[1,1,0] op_sel_hi:[1,0,1] neg_lo:[0,1,0]"
            : "+v"(y) : "v"(k), "v"(x));
    else
        asm("v_pk_fma_f32 %0, %1, %2, %0 op_sel:[1,1,0] op_sel_hi:[1,0,1] neg_lo:[1,1,0] neg_hi:[1,0,0]"
            : "+v"(y) : "v"(k), "v"(x));
    return y;
}
template<int NEGLO, int NEGHI>
__device__ __forceinline__ void cmac(v2f& y, v2f k, v2f x) {
    if constexpr (!NEGLO)
        asm("v_pk_fma_f32 %0, %1, %2, %0 op_sel:[0,0,0] op_sel_hi:[0,1,1]"
            : "+v"(y) : "v"(k), "v"(x));
    else
        asm("v_pk_fma_f32 %0, %1, %2, %0 op_sel:[0,0,0] op_sel_hi:[0,1,1] neg_lo:[1,0,0] neg_hi:[1,0,0]"
            : "+v"(y) : "v"(k), "v"(x));
    if constexpr (!NEGHI)
        asm("v_pk_fma_f32 %0, %1, %2, %0 op_sel:[1,1,0] op_sel_hi:[1,0,1] neg_lo:[0,1,0]"
            : "+v"(y) : "v"(k), "v"(x));
    else
        asm("v_pk_fma_f32 %0, %1, %2, %0 op_sel:[1,1,0] op_sel_hi:[1,0,1] neg_lo:[1,1,0] neg_hi:[1,0,0]"
            : "+v"(y) : "v"(k), "v"(x));
}
template<bool CS> __device__ __forceinline__ v2f  cmulA(v2f k, v2f x) { return cmul<0, CS ? 1 : 0>(k, x); }
template<bool CS> __device__ __forceinline__ void cmacB(v2f& y, v2f k, v2f x) { cmac<CS ? 1 : 0, 0>(y, k, x); }

// ---------------- gate sub-block [Q0, Q1) of phase P (registers only) ----------------
template<int P, int Q0, int Q1>
__device__ __forceinline__ void gates(v2f* x, const float4* __restrict__ umat, unsigned tid)
{
    static_for<Q1 - Q0>([&](auto Qc) {
        constexpr int q = Q0 + (int)decltype(Qc)::value;
        if constexpr (q < ((P < 10) ? 4 : 2)) {
            constexpr unsigned cp  = SC3.cp[P][q];
            constexpr unsigned pvm = SC3.pv[P][q];
            const float4 u = umat[4 * P + q];
            const unsigned sm = ((unsigned)__popc(tid & pvm)) << 31;
            v2f A, B;  // A = (ar, ai^s), B = (br^s, bi)
            A.x = u.x; A.y = __uint_as_float(__float_as_uint(u.y) ^ sm);
            B.x = __uint_as_float(__float_as_uint(u.z) ^ sm); B.y = u.w;
            static_for<8>([&](auto Pp) {
                constexpr unsigned pp   = decltype(Pp)::value;
                constexpr unsigned lowm = (1u << q) - 1u;
                constexpr unsigned s0   = ((pp & ~lowm) << 1) | (pp & lowm);
                constexpr unsigned s1   = s0 | (1u << q);
                constexpr bool c0 = (cp >> s0) & 1u;
                constexpr bool c1 = (cp >> s1) & 1u;
                const v2f x0 = x[s0], x1 = x[s1];
                v2f y0 = cmulA<c0>(A, x0); cmacB<c0>(y0, B, x1);
                v2f y1 = cmulA<c1>(A, x1); cmacB<c1>(y1, B, x0);
                x[s0] = y0; x[s1] = y1;
            });
        }
    });
}

// contiguous conflict-free reads: one base + immediate offsets
__device__ __forceinline__ void rdall(v2f* x, const char* psiB, unsigned rbase) {
    static_for<16>([&](auto Sc) {
        constexpr int s = (int)decltype(Sc)::value;
        x[s] = *(const v2f*)(psiB + rbase + (s << 9));
    });
}

// write phase-P output into frame P+1
template<int P>
__device__ __forceinline__ void wrt(char* psiB, unsigned tid, const v2f* x) {
    unsigned wi = ((tid >> 6) & 15u) << 10;
    static_for<6>([&](auto Bc) {
        constexpr int b = (int)decltype(Bc)::value;
        constexpr unsigned m = SC3.WT[P][b];
        wi ^= m & (unsigned)(-(int)((tid >> b) & 1u));
    });
    const unsigned wib = wi << 3;
    static_for<16>([&](auto Sc) {
        constexpr int s = (int)decltype(Sc)::value;
        constexpr unsigned off = SC3.WS[P][s] << 3;
        *(v2f*)(psiB + (wib ^ off)) = x[s];
    });
}

// stage one row into the phase-0 frame from 4 prefetched float4s (imag = 0)
__device__ __forceinline__ void stageWreg(char* psiB, const float4* v, unsigned sidx) {
    static_for<4>([&](auto Kc) {
        constexpr int k = (int)decltype(Kc)::value;
        const unsigned bi = sidx ^ SC3.STK[k];
        *(v2f*)(psiB + ((bi ^ SC3.STJ[0]) << 3)) = (v2f){ v[k].x, 0.f };
        *(v2f*)(psiB + ((bi ^ SC3.STJ[1]) << 3)) = (v2f){ v[k].y, 0.f };
        *(v2f*)(psiB + ((bi ^ SC3.STJ[2]) << 3)) = (v2f){ v[k].z, 0.f };
        *(v2f*)(psiB + ((bi ^ SC3.STJ[3]) << 3)) = (v2f){ v[k].w, 0.f };
    });
}

__global__ __launch_bounds__(TPB, 4) void qsim_kernel(
    const float* __restrict__ state,
    const float* __restrict__ params,
    const float* __restrict__ head_w,
    const float* __restrict__ head_b,
    float* __restrict__ out)
{
    __shared__ v2f    psi[DIM];          // 128 KB: one full frame, shared A/B alternately
    __shared__ float4 umat[NG];
    __shared__ float  red[2 * (TPB / 64)];
    char* psiB = (char*)psi;
    const unsigned tid = threadIdx.x;

    // Fused U = RY(t2)*RX(t1) = [[a,b],[-conj(b),conj(a)]]; a=(c1c2,s1s2), b=(-s2c1,-c2s1)
    if (tid < NG) {
        float t1 = 0.5f * params[2 * tid + 0];
        float t2 = 0.5f * params[2 * tid + 1];
        float s1, c1, s2, c2;
        sincosf(t1, &s1, &c1);
        sincosf(t2, &s2, &c2);
        umat[tid] = make_float4(c1 * c2, s1 * s2, -s2 * c1, -c2 * s1);
    }

    const float4* st4A = reinterpret_cast<const float4*>(state + (size_t)(2 * blockIdx.x) * DIM);
    const float4* st4B = st4A + DIM / 4;

    unsigned sidx = 0;
    static_for<10>([&](auto Bc) {
        constexpr int b = (int)decltype(Bc)::value;
        sidx ^= SC3.ST[b] & (unsigned)(-(int)((tid >> b) & 1u));
    });
    // frame layout: byte = [wave(tid6..9) <<13 | slot <<9 | lane(tid0..5) <<3]
    const unsigned rbase = ((tid >> 6) << 13) | ((tid & 63u) << 3);

    v2f xA[16], xB[16];

    // ---- prologue: load+stage A; prefetch B early (HBM latency hides under A)
    float4 vA[4], vB[4];
    static_for<4>([&](auto Kc) {
        constexpr int k = (int)decltype(Kc)::value;
        vA[k] = st4A[tid + k * TPB];
        vB[k] = st4B[tid + k * TPB];
    });
    stageWreg(psiB, vA, sidx);
    __syncthreads();
    rdall(xA, psiB, rbase);
    __syncthreads();
    stageWreg(psiB, vB, sidx);     // B staging writes overlap A's phase-0 gates
    gates<0, 0, 4>(xA, umat, tid);
    __syncthreads();
    rdall(xB, psiB, rbase);
    __syncthreads();

    // ---- dual-element pipeline, gate blocks split 2+2 around each LDS burst:
    //      write burst hides under gates[0:2], read burst under gates[2:4]
    static_for<10>([&](auto Pc) {
        constexpr int P = (int)decltype(Pc)::value;
        wrt<P>(psiB, tid, xA);              // frame := A.f(P+1)  (B.f(P) consumed)
        gates<P, 0, 2>(xB, umat, tid);
        __syncthreads();
        rdall(xA, psiB, rbase);             // reads issue first...
        gates<P, 2, 4>(xB, umat, tid);      // ...VALU covers them
        __syncthreads();
        wrt<P>(psiB, tid, xB);              // frame := B.f(P+1)  (A.f(P+1) consumed)
        gates<P + 1, 0, 2>(xA, umat, tid);
        __syncthreads();
        rdall(xB, psiB, rbase);
        gates<P + 1, 2, 4>(xA, umat, tid);
        __syncthreads();
    });
    gates<10, 0, 4>(xB, umat, tid);

    // ---- measurement from registers (coefficients shared by A and B)
    float e[NW];
    static_for<NW>([&](auto Wc) {
        constexpr int w = (int)decltype(Wc)::value;
        constexpr unsigned pzw = SC3.pz[w];
        float hw = head_w[w];
        e[w] = (__popc(tid & pzw) & 1) ? -hw : hw;
    });
    float c[16];
    static_for<16>([&](auto Mc) { c[decltype(Mc)::value] = 0.f; });
    static_for<NW>([&](auto Wc) {
        constexpr int w = (int)decltype(Wc)::value;
        c[SC3.nib[w]] += e[w];
    });
    static_for<4>([&](auto Bc) {
        constexpr unsigned B = 1u << decltype(Bc)::value;
        static_for<16>([&](auto Kc) {
            constexpr unsigned k = decltype(Kc)::value;
            if constexpr (!(k & B)) {
                float a = c[k], b = c[k | B];
                c[k] = a + b; c[k | B] = a - b;
            }
        });
    });
    float accA = 0.f, accB = 0.f;
    static_for<16>([&](auto Sc) {
        constexpr int s = (int)decltype(Sc)::value;
        accA += (xA[s].x * xA[s].x + xA[s].y * xA[s].y) * c[s];
        accB += (xB[s].x * xB[s].x + xB[s].y * xB[s].y) * c[s];
    });

#pragma unroll
    for (int off = 32; off > 0; off >>= 1) {
        accA += __shfl_down(accA, off, 64);
        accB += __shfl_down(accB, off, 64);
    }
    const unsigned lane = tid & 63, wv = tid >> 6;
    if (lane == 0) { red[wv] = accA; red[(TPB / 64) + wv] = accB; }
    __syncthreads();
    if (tid == 0) {
        float tA = 0.f, tB = 0.f;
#pragma unroll
        for (int i = 0; i < TPB / 64; ++i) { tA += red[i]; tB += red[(TPB / 64) + i]; }
        out[2 * blockIdx.x + 0] = tA + head_b[0];
        out[2 * blockIdx.x + 1] = tB + head_b[0];
    }
}

extern "C" void kernel_launch(void* const* d_in, const int* in_sizes, int n_in,
                              void* d_out, int out_size, void* d_ws, size_t ws_size,
                              hipStream_t stream) {
    const float* state  = (const float*)d_in[0];   // (1024, 16384) f32
    const float* params = (const float*)d_in[1];   // (3, 14, 2) f32
    const float* head_w = (const float*)d_in[2];   // (1, 14) f32
    const float* head_b = (const float*)d_in[3];   // (1,) f32
    float* out = (float*)d_out;                    // (1024,) f32

    qsim_kernel<<<out_size / 2, TPB, 0, stream>>>(state, params, head_w, head_b, out);
}

// Round 14
// 128.117 us; speedup vs baseline: 1.0233x; 1.0233x over previous
//
#include <hip/hip_runtime.h>
#include <utility>

#define NW 14
#define NL 3
#define DIM 16384            // 2^14
#define NG  (NL * NW)        // 42 fused RY*RX gates
#define TPB 1024
#define NPH3 11              // 10 phases of 4 gates + 1 phase of 2

typedef float v2f __attribute__((ext_vector_type(2)));

struct S3 {
    int ok = 1;
    unsigned Lane[NPH3][6] = {};   // lane dirs (tid bits 0..5) per phase
    unsigned Reg[NPH3][4]  = {};   // register/slot dirs per phase
    unsigned Vw[4]         = {};   // global wave dirs (tid bits 6..9)
    unsigned WT[NPH3][6]   = {};   // write consts: coords of lane dirs in NEXT frame
    unsigned WS[NPH3][16]  = {};   // write consts: coords of slot XORs in NEXT frame
    unsigned pv[NPH3][4]   = {};   // runtime sign: 10-bit tid parity mask per gate
    unsigned cp[NPH3][4]   = {};   // compile-time per-slot role bits per gate
    unsigned ST[10] = {}, STK[4] = {}, STJ[4] = {};   // staging coords (phase-0 frame)
    unsigned pz[NW] = {}, nib[NW] = {};               // measurement maps
};

// ---- cheap incremental echelon (no coords) ----
struct Bas14 { unsigned piv[14] = {}; int n = 0; };
constexpr bool binsert(Bas14& B, unsigned v) {
    unsigned x = v;
    for (int bit = 13; bit >= 0; --bit) {
        if (!((x >> bit) & 1u)) continue;
        if (B.piv[bit]) x ^= B.piv[bit];
        else { B.piv[bit] = x; ++B.n; return true; }
    }
    return false;
}

// ---- echelon with coordinate tracking: built ONCE per basis, cheap solves ----
struct Ech { unsigned pv14[14] = {}; unsigned pc14[14] = {}; int ok = 1; };
constexpr Ech mkech(const unsigned bas[14]) {
    Ech E{};
    for (int b = 0; b < 14; ++b) {
        unsigned x = bas[b], c = 1u << b;
        for (int bit = 13; bit >= 0; --bit) {
            if (!((x >> bit) & 1u)) continue;
            if (E.pv14[bit]) { x ^= E.pv14[bit]; c ^= E.pc14[bit]; }
            else { E.pv14[bit] = x; E.pc14[bit] = c; x = 0; break; }
        }
        if (x) E.ok = 0;
    }
    return E;
}
constexpr unsigned coordsE(const Ech& E, unsigned v, int& ok) {
    unsigned x = v, c = 0;
    for (int bit = 13; bit >= 0; --bit) {
        if ((x >> bit) & 1u) {
            if (!E.pv14[bit]) { ok = 0; return 0; }
            x ^= E.pv14[bit]; c ^= E.pc14[bit];
        }
    }
    return c;
}

constexpr S3 build3(int vskip) {
    S3 S{};
    unsigned mk[NG] = {}, vmg[NG] = {}, zm[NW] = {};
    {
        unsigned A[NW] = {};
        for (int w = 0; w < NW; ++w) A[w] = 1u << (NW - 1 - w);
        int g = 0;
        for (int l = 0; l < NL; ++l) {
            unsigned rows[NW] = {};
            for (int u = 0; u < NW; ++u) rows[u] = A[u] | (1u << (NW + u));
            for (int col = 0; col < NW; ++col) {
                int piv = col;
                while (piv < NW && !((rows[piv] >> col) & 1u)) ++piv;
                if (piv >= NW) { S.ok = 0; continue; }
                unsigned tmp = rows[col]; rows[col] = rows[piv]; rows[piv] = tmp;
                for (int r = 0; r < NW; ++r)
                    if (r != col && ((rows[r] >> col) & 1u)) rows[r] ^= rows[col];
            }
            for (int w = 0; w < NW; ++w) {
                unsigned m = 0;
                for (int r = 0; r < NW; ++r) m |= ((rows[r] >> (NW + w)) & 1u) << r;
                mk[g] = m; vmg[g] = A[w]; ++g;
            }
            for (int w = 0; w < NW - 1; ++w) A[w + 1] ^= A[w];  // virtual CNOT chain
            A[0] ^= A[NW - 1];
        }
        for (int w = 0; w < NW; ++w) zm[w] = A[w];
    }
    for (int p = 0; p < NPH3; ++p) {
        int J = (p < 10) ? 4 : 2;
        for (int q = 0; q < J; ++q) S.Reg[p][q] = mk[4 * p + q];
    }
    // global wave dirs: random 4-dim subspace independent of every group span
    {
        Bas14 gb[6] = {};
        for (int g = 0; g < 6; ++g) {
            int nm = (g < 5) ? 8 : 2;
            for (int i = 0; i < nm; ++i) binsert(gb[g], mk[8 * g + i]);
        }
        int found = 0, skipped = 0;
        for (unsigned seed = 1; seed < 512u && !found; ++seed) {
            unsigned cand[4] = {};
            for (int i = 0; i < 4; ++i) {
                unsigned h = (seed * 2654435761u) ^ ((unsigned)(i + 1) * 0x9E3779B9u);
                h ^= h >> 15; h *= 2246822519u; h ^= h >> 13; h *= 3266489917u; h ^= h >> 16;
                cand[i] = h & 0x3FFFu;
            }
            Bas14 cb{};
            bool good = binsert(cb, cand[0]) && binsert(cb, cand[1])
                     && binsert(cb, cand[2]) && binsert(cb, cand[3]);
            for (int g = 0; g < 6 && good; ++g) {
                Bas14 t = gb[g];
                for (int i = 0; i < 4 && good; ++i)
                    if (!binsert(t, cand[i])) good = false;
            }
            if (good) {
                if (skipped < vskip) { ++skipped; continue; }
                for (int i = 0; i < 4; ++i) S.Vw[i] = cand[i];
                found = 1;
            }
        }
        if (!found) S.ok = 0;
    }
    // per group: fillers and raw lane dirs (incremental echelon)
    for (int g = 0; g < 6; ++g) {
        int nm = (g < 5) ? 8 : 2;
        Bas14 B{};
        for (int i = 0; i < 4; ++i) binsert(B, S.Vw[i]);
        for (int i = 0; i < nm; ++i) binsert(B, mk[8 * g + i]);
        unsigned fill[12] = {}; int nf = 0;
        for (int b = 0; b < 14 && B.n < 14; ++b)
            if (binsert(B, 1u << b)) fill[nf++] = 1u << b;
        if (B.n != 14) S.ok = 0;
        if (g < 5) {
            int pA = 2 * g, pB = 2 * g + 1;
            for (int b = 0; b < 4; ++b) { S.Lane[pA][b] = S.Reg[pB][b]; S.Lane[pB][b] = S.Reg[pA][b]; }
            S.Lane[pA][4] = fill[0]; S.Lane[pA][5] = fill[1];
            S.Lane[pB][4] = fill[0]; S.Lane[pB][5] = fill[1];
        } else {
            S.Reg[10][2] = fill[0]; S.Reg[10][3] = fill[1];
            for (int b = 0; b < 6; ++b) S.Lane[10][b] = fill[2 + b];
        }
    }
    // transitions in reverse (echelon built once per transition)
    for (int t = NPH3 - 2; t >= 0; --t) {
        unsigned bas[14] = {};
        for (int b = 0; b < 6; ++b) bas[b] = S.Lane[t + 1][b];
        for (int q = 0; q < 4; ++q) bas[6 + q] = S.Reg[t + 1][q];
        for (int j = 0; j < 4; ++j) bas[10 + j] = S.Vw[j];
        Ech E = mkech(bas);
        if (!E.ok) S.ok = 0;
        unsigned rb[4] = {}; int rn = 0;
        for (int b = 0; b < 6; ++b) {
            int bestcs = 0, bestg = -1; unsigned bestr = 0;
            for (int cs = 0; cs < 16; ++cs) {
                unsigned c = 0;
                for (int q = 0; q < 4; ++q) if ((cs >> q) & 1) c ^= S.Reg[t][q];
                int ok2 = 1;
                unsigned r = coordsE(E, S.Lane[t][b] ^ c, ok2) & 15u;
                if (!ok2) continue;
                unsigned x = r;
                for (int i = 0; i < rn; ++i) {
                    int hb = 3; while (hb > 0 && !((rb[i] >> hb) & 1u)) --hb;
                    if ((x >> hb) & 1u) x ^= rb[i];
                }
                int gain = x ? 1 : 0;
                if (gain > bestg) { bestg = gain; bestcs = cs; bestr = r; }
                if (gain == 1) break;
            }
            unsigned c = 0;
            for (int q = 0; q < 4; ++q) if ((bestcs >> q) & 1) c ^= S.Reg[t][q];
            S.Lane[t][b] ^= c;
            unsigned x = bestr;
            for (int i = 0; i < rn; ++i) {
                int hb = 3; while (hb > 0 && !((rb[i] >> hb) & 1u)) --hb;
                if ((x >> hb) & 1u) x ^= rb[i];
            }
            if (x && rn < 4) rb[rn++] = x;
        }
        int okc = 1;
        for (int b = 0; b < 6; ++b) S.WT[t][b] = coordsE(E, S.Lane[t][b], okc);
        for (int s = 0; s < 16; ++s) {
            unsigned v = 0;
            for (int q = 0; q < 4; ++q) if ((s >> q) & 1) v ^= S.Reg[t][q];
            S.WS[t][s] = coordsE(E, v, okc);
        }
        if (!okc) S.ok = 0;
        // intra-group (even t) transitions must be wave-local: no Vw components.
        // Structural: Lane[t],Reg[t] lie in span(group ∪ fills) which is exactly
        // span(Lane[t+1] ∪ Reg[t+1]) for the pA->pB transition.
        if ((t & 1) == 0) {
            for (int b = 0; b < 6; ++b) if (S.WT[t][b] >> 10) S.ok = 0;
            for (int s = 0; s < 16; ++s) if (S.WS[t][s] >> 10) S.ok = 0;
        }
        // verify: reader-amp(writer-idx) == writer-amp on basis inputs
        for (int ub = 0; ub < 10; ++ub) {
            unsigned wamp = (ub < 6) ? S.Lane[t][ub] : S.Vw[ub - 6];
            unsigned widx = (ub < 6) ? S.WT[t][ub] : (1u << (10 + ub - 6));
            unsigned ramp = 0;
            for (int b = 0; b < 6; ++b) if ((widx >> b) & 1u) ramp ^= S.Lane[t + 1][b];
            for (int q = 0; q < 4; ++q) if ((widx >> (6 + q)) & 1u) ramp ^= S.Reg[t + 1][q];
            for (int j = 0; j < 4; ++j) if ((widx >> (10 + j)) & 1u) ramp ^= S.Vw[j];
            if (ramp != wamp) S.ok = 0;
        }
        for (int q = 0; q < 4; ++q) {
            unsigned widx = S.WS[t][1u << q];
            unsigned ramp = 0;
            for (int b = 0; b < 6; ++b) if ((widx >> b) & 1u) ramp ^= S.Lane[t + 1][b];
            for (int qq = 0; qq < 4; ++qq) if ((widx >> (6 + qq)) & 1u) ramp ^= S.Reg[t + 1][qq];
            for (int j = 0; j < 4; ++j) if ((widx >> (10 + j)) & 1u) ramp ^= S.Vw[j];
            if (ramp != S.Reg[t][q]) S.ok = 0;
        }
    }
    // signs
    for (int p = 0; p < NPH3; ++p) {
        int J = (p < 10) ? 4 : 2;
        for (int q = 0; q < J; ++q) {
            unsigned vm = vmg[4 * p + q], pvm = 0;
            for (int b = 0; b < 6; ++b)
                if (__builtin_popcount(S.Lane[p][b] & vm) & 1) pvm |= 1u << b;
            for (int j = 0; j < 4; ++j)
                if (__builtin_popcount(S.Vw[j] & vm) & 1) pvm |= 1u << (6 + j);
            S.pv[p][q] = pvm;
            unsigned cpm = 0;
            for (int s = 0; s < 16; ++s) {
                unsigned v = 0;
                for (int q2 = 0; q2 < 4; ++q2) if ((s >> q2) & 1) v ^= S.Reg[p][q2];
                if (__builtin_popcount(v & vm) & 1) cpm |= 1u << s;
            }
            S.cp[p][q] = cpm;
        }
    }
    // staging coords + verification
    {
        unsigned bas[14] = {};
        for (int b = 0; b < 6; ++b) bas[b] = S.Lane[0][b];
        for (int q = 0; q < 4; ++q) bas[6 + q] = S.Reg[0][q];
        for (int j = 0; j < 4; ++j) bas[10 + j] = S.Vw[j];
        Ech E = mkech(bas);
        if (!E.ok) S.ok = 0;
        int okc = 1;
        for (int b = 0; b < 10; ++b) S.ST[b] = coordsE(E, 1u << (b + 2), okc);
        for (int k = 0; k < 4; ++k) S.STK[k] = coordsE(E, (unsigned)k << 12, okc);
        for (int j = 0; j < 4; ++j) S.STJ[j] = coordsE(E, (unsigned)j, okc);
        if (!okc) S.ok = 0;
        for (int ub = 0; ub < 18; ++ub) {
            unsigned amp = (ub < 10) ? (1u << (ub + 2))
                         : (ub < 14) ? ((unsigned)(ub - 10) << 12) : (unsigned)(ub - 14);
            unsigned widx = (ub < 10) ? S.ST[ub] : (ub < 14) ? S.STK[ub - 10] : S.STJ[ub - 14];
            unsigned ramp = 0;
            for (int b = 0; b < 6; ++b) if ((widx >> b) & 1u) ramp ^= S.Lane[0][b];
            for (int q = 0; q < 4; ++q) if ((widx >> (6 + q)) & 1u) ramp ^= S.Reg[0][q];
            for (int j = 0; j < 4; ++j) if ((widx >> (10 + j)) & 1u) ramp ^= S.Vw[j];
            if (ramp != amp) S.ok = 0;
        }
    }
    // measurement from phase-10 registers
    for (int w = 0; w < NW; ++w) {
        unsigned pzm = 0;
        for (int b = 0; b < 6; ++b)
            if (__builtin_popcount(S.Lane[10][b] & zm[w]) & 1) pzm |= 1u << b;
        for (int j = 0; j < 4; ++j)
            if (__builtin_popcount(S.Vw[j] & zm[w]) & 1) pzm |= 1u << (6 + j);
        S.pz[w] = pzm;
        unsigned nv = 0;
        for (int q = 0; q < 4; ++q)
            if (__builtin_popcount(S.Reg[10][q] & zm[w]) & 1) nv |= 1u << q;
        S.nib[w] = nv;
    }
    return S;
}
constexpr S3 pickBuild() {
    for (int v = 0; v < 4; ++v) {
        S3 s = build3(v);
        if (s.ok) return s;
    }
    S3 bad{}; bad.ok = 0; return bad;
}
constexpr S3 SC3 = pickBuild();
static_assert(SC3.ok == 1, "schedule build failed");

// ---------------- static_for ----------------
template<class F, unsigned... I>
__device__ __forceinline__ void static_for_impl(F&& f, std::integer_sequence<unsigned, I...>) {
    (f(std::integral_constant<unsigned, I>{}), ...);
}
template<unsigned N, class F>
__device__ __forceinline__ void static_for(F&& f) {
    static_for_impl(static_cast<F&&>(f), std::make_integer_sequence<unsigned, N>{});
}

// ---------------- packed complex mul/mac (verified r4..r13) ----------------
template<int NEGLO, int NEGHI>
__device__ __forceinline__ v2f cmul(v2f k, v2f x) {
    v2f y;
    if constexpr (!NEGLO)
        asm("v_pk_mul_f32 %0, %1, %2 op_sel:[0,0] op_sel_hi:[0,1]"
            : "=&v"(y) : "v"(k), "v"(x));
    else
        asm("v_pk_mul_f32 %0, %1, %2 op_sel:[0,0] op_sel_hi:[0,1] neg_lo:[1,0] neg_hi:[1,0]"
            : "=&v"(y) : "v"(k), "v"(x));
    if constexpr (!NEGHI)
        asm("v_pk_fma_f32 %0, %1, %2, %0 op_sel:[1,1,0] op_sel_hi:[1,0,1] neg_lo:[0,1,0]"
            : "+v"(y) : "v"(k), "v"(x));
    else
        asm("v_pk_fma_f32 %0, %1, %2, %0 op_sel:[1,1,0] op_sel_hi:[1,0,1] neg_lo:[1,1,0] neg_hi:[1,0,0]"
            : "+v"(y) : "v"(k), "v"(x));
    return y;
}
template<int NEGLO, int NEGHI>
__device__ __forceinline__ void cmac(v2f& y, v2f k, v2f x) {
    if constexpr (!NEGLO)
        asm("v_pk_fma_f32 %0, %1, %2, %0 op_sel:[0,0,0] op_sel_hi:[0,1,1]"
            : "+v"(y) : "v"(k), "v"(x));
    else
        asm("v_pk_fma_f32 %0, %1, %2, %0 op_sel:[0,0,0] op_sel_hi:[0,1,1] neg_lo:[1,0,0] neg_hi:[1,0,0]"
            : "+v"(y) : "v"(k), "v"(x));
    if constexpr (!NEGHI)
        asm("v_pk_fma_f32 %0, %1, %2, %0 op_sel:[1,1,0] op_sel_hi:[1,0,1] neg_lo:[0,1,0]"
            : "+v"(y) : "v"(k), "v"(x));
    else
        asm("v_pk_fma_f32 %0, %1, %2, %0 op_sel:[1,1,0] op_sel_hi:[1,0,1] neg_lo:[1,1,0] neg_hi:[1,0,0]"
            : "+v"(y) : "v"(k), "v"(x));
}
template<bool CS> __device__ __forceinline__ v2f  cmulA(v2f k, v2f x) { return cmul<0, CS ? 1 : 0>(k, x); }
template<bool CS> __device__ __forceinline__ void cmacB(v2f& y, v2f k, v2f x) { cmac<CS ? 1 : 0, 0>(y, k, x); }

// ---------------- gate sub-block [Q0, Q1) of phase P (registers only) ----------------
template<int P, int Q0, int Q1>
__device__ __forceinline__ void gates(v2f* x, const float4* __restrict__ umat, unsigned tid)
{
    static_for<Q1 - Q0>([&](auto Qc) {
        constexpr int q = Q0 + (int)decltype(Qc)::value;
        if constexpr (q < ((P < 10) ? 4 : 2)) {
            constexpr unsigned cp  = SC3.cp[P][q];
            constexpr unsigned pvm = SC3.pv[P][q];
            const float4 u = umat[4 * P + q];
            const unsigned sm = ((unsigned)__popc(tid & pvm)) << 31;
            v2f A, B;  // A = (ar, ai^s), B = (br^s, bi)
            A.x = u.x; A.y = __uint_as_float(__float_as_uint(u.y) ^ sm);
            B.x = __uint_as_float(__float_as_uint(u.z) ^ sm); B.y = u.w;
            static_for<8>([&](auto Pp) {
                constexpr unsigned pp   = decltype(Pp)::value;
                constexpr unsigned lowm = (1u << q) - 1u;
                constexpr unsigned s0   = ((pp & ~lowm) << 1) | (pp & lowm);
                constexpr unsigned s1   = s0 | (1u << q);
                constexpr bool c0 = (cp >> s0) & 1u;
                constexpr bool c1 = (cp >> s1) & 1u;
                const v2f x0 = x[s0], x1 = x[s1];
                v2f y0 = cmulA<c0>(A, x0); cmacB<c0>(y0, B, x1);
                v2f y1 = cmulA<c1>(A, x1); cmacB<c1>(y1, B, x0);
                x[s0] = y0; x[s1] = y1;
            });
        }
    });
}

// contiguous conflict-free reads: one base + immediate offsets
__device__ __forceinline__ void rdall(v2f* x, const char* psiB, unsigned rbase) {
    static_for<16>([&](auto Sc) {
        constexpr int s = (int)decltype(Sc)::value;
        x[s] = *(const v2f*)(psiB + rbase + (s << 9));
    });
}

// write phase-P output into frame P+1
template<int P>
__device__ __forceinline__ void wrt(char* psiB, unsigned tid, const v2f* x) {
    unsigned wi = ((tid >> 6) & 15u) << 10;
    static_for<6>([&](auto Bc) {
        constexpr int b = (int)decltype(Bc)::value;
        constexpr unsigned m = SC3.WT[P][b];
        wi ^= m & (unsigned)(-(int)((tid >> b) & 1u));
    });
    const unsigned wib = wi << 3;
    static_for<16>([&](auto Sc) {
        constexpr int s = (int)decltype(Sc)::value;
        constexpr unsigned off = SC3.WS[P][s] << 3;
        *(v2f*)(psiB + (wib ^ off)) = x[s];
    });
}

// stage one row into the phase-0 frame from 4 prefetched float4s (imag = 0)
__device__ __forceinline__ void stageWreg(char* psiB, const float4* v, unsigned sidx) {
    static_for<4>([&](auto Kc) {
        constexpr int k = (int)decltype(Kc)::value;
        const unsigned bi = sidx ^ SC3.STK[k];
        *(v2f*)(psiB + ((bi ^ SC3.STJ[0]) << 3)) = (v2f){ v[k].x, 0.f };
        *(v2f*)(psiB + ((bi ^ SC3.STJ[1]) << 3)) = (v2f){ v[k].y, 0.f };
        *(v2f*)(psiB + ((bi ^ SC3.STJ[2]) << 3)) = (v2f){ v[k].z, 0.f };
        *(v2f*)(psiB + ((bi ^ SC3.STJ[3]) << 3)) = (v2f){ v[k].w, 0.f };
    });
}

__global__ __launch_bounds__(TPB, 4) void qsim_kernel(
    const float* __restrict__ state,
    const float* __restrict__ params,
    const float* __restrict__ head_w,
    const float* __restrict__ head_b,
    float* __restrict__ out)
{
    __shared__ v2f    psi[DIM];          // 128 KB: one full frame, shared A/B alternately
    __shared__ float4 umat[NG];
    __shared__ float  red[2 * (TPB / 64)];
    char* psiB = (char*)psi;
    const unsigned tid = threadIdx.x;

    // Fused U = RY(t2)*RX(t1) = [[a,b],[-conj(b),conj(a)]]; a=(c1c2,s1s2), b=(-s2c1,-c2s1)
    if (tid < NG) {
        float t1 = 0.5f * params[2 * tid + 0];
        float t2 = 0.5f * params[2 * tid + 1];
        float s1, c1, s2, c2;
        sincosf(t1, &s1, &c1);
        sincosf(t2, &s2, &c2);
        umat[tid] = make_float4(c1 * c2, s1 * s2, -s2 * c1, -c2 * s1);
    }

    const float4* st4A = reinterpret_cast<const float4*>(state + (size_t)(2 * blockIdx.x) * DIM);
    const float4* st4B = st4A + DIM / 4;

    unsigned sidx = 0;
    static_for<10>([&](auto Bc) {
        constexpr int b = (int)decltype(Bc)::value;
        sidx ^= SC3.ST[b] & (unsigned)(-(int)((tid >> b) & 1u));
    });
    // frame layout: byte = [wave(tid6..9) <<13 | slot <<9 | lane(tid0..5) <<3]
    const unsigned rbase = ((tid >> 6) << 13) | ((tid & 63u) << 3);

    v2f xA[16], xB[16];

    // ---- prologue: load+stage A; prefetch B early (HBM latency hides under A)
    float4 vA[4], vB[4];
    static_for<4>([&](auto Kc) {
        constexpr int k = (int)decltype(Kc)::value;
        vA[k] = st4A[tid + k * TPB];
        vB[k] = st4B[tid + k * TPB];
    });
    stageWreg(psiB, vA, sidx);
    __syncthreads();
    rdall(xA, psiB, rbase);
    __syncthreads();
    stageWreg(psiB, vB, sidx);     // B staging writes overlap A's phase-0 gates
    gates<0, 0, 4>(xA, umat, tid);
    __syncthreads();
    rdall(xB, psiB, rbase);
    __syncthreads();

    // ---- dual-element pipeline.
    // Even P (intra-group): ALL LDS traffic is wave-local (build-verified:
    // WT/WS have zero Vw coords) -> no barriers; waves free-run and de-sync.
    // Odd P (cross-group): barrier-fenced, gates split 2+2 around bursts.
    static_for<10>([&](auto Pc) {
        constexpr int P = (int)decltype(Pc)::value;
        if constexpr ((P & 1) == 0) {
            wrt<P>(psiB, tid, xA);              // own region (wave-local)
            gates<P, 0, 4>(xB, umat, tid);
            rdall(xA, psiB, rbase);             // own region; in-wave DS order
            wrt<P>(psiB, tid, xB);
            gates<P + 1, 0, 2>(xA, umat, tid);
            rdall(xB, psiB, rbase);
            gates<P + 1, 2, 4>(xA, umat, tid);
        } else {
            __syncthreads();                    // all waves' local reads done
            wrt<P>(psiB, tid, xA);              // cross-region
            gates<P, 0, 2>(xB, umat, tid);
            __syncthreads();
            rdall(xA, psiB, rbase);
            gates<P, 2, 4>(xB, umat, tid);
            __syncthreads();
            wrt<P>(psiB, tid, xB);
            gates<P + 1, 0, 2>(xA, umat, tid);
            __syncthreads();
            rdall(xB, psiB, rbase);
            gates<P + 1, 2, 4>(xA, umat, tid);
        }
    });
    gates<10, 0, 4>(xB, umat, tid);

    // ---- measurement from registers (coefficients shared by A and B)
    float e[NW];
    static_for<NW>([&](auto Wc) {
        constexpr int w = (int)decltype(Wc)::value;
        constexpr unsigned pzw = SC3.pz[w];
        float hw = head_w[w];
        e[w] = (__popc(tid & pzw) & 1) ? -hw : hw;
    });
    float c[16];
    static_for<16>([&](auto Mc) { c[decltype(Mc)::value] = 0.f; });
    static_for<NW>([&](auto Wc) {
        constexpr int w = (int)decltype(Wc)::value;
        c[SC3.nib[w]] += e[w];
    });
    static_for<4>([&](auto Bc) {
        constexpr unsigned B = 1u << decltype(Bc)::value;
        static_for<16>([&](auto Kc) {
            constexpr unsigned k = decltype(Kc)::value;
            if constexpr (!(k & B)) {
                float a = c[k], b = c[k | B];
                c[k] = a + b; c[k | B] = a - b;
            }
        });
    });
    float accA = 0.f, accB = 0.f;
    static_for<16>([&](auto Sc) {
        constexpr int s = (int)decltype(Sc)::value;
        accA += (xA[s].x * xA[s].x + xA[s].y * xA[s].y) * c[s];
        accB += (xB[s].x * xB[s].x + xB[s].y * xB[s].y) * c[s];
    });

#pragma unroll
    for (int off = 32; off > 0; off >>= 1) {
        accA += __shfl_down(accA, off, 64);
        accB += __shfl_down(accB, off, 64);
    }
    const unsigned lane = tid & 63, wv = tid >> 6;
    if (lane == 0) { red[wv] = accA; red[(TPB / 64) + wv] = accB; }
    __syncthreads();
    if (tid == 0) {
        float tA = 0.f, tB = 0.f;
#pragma unroll
        for (int i = 0; i < TPB / 64; ++i) { tA += red[i]; tB += red[(TPB / 64) + i]; }
        out[2 * blockIdx.x + 0] = tA + head_b[0];
        out[2 * blockIdx.x + 1] = tB + head_b[0];
    }
}

extern "C" void kernel_launch(void* const* d_in, const int* in_sizes, int n_in,
                              void* d_out, int out_size, void* d_ws, size_t ws_size,
                              hipStream_t stream) {
    const float* state  = (const float*)d_in[0];   // (1024, 16384) f32
    const float* params = (const float*)d_in[1];   // (3, 14, 2) f32
    const float* head_w = (const float*)d_in[2];   // (1, 14) f32
    const float* head_b = (const float*)d_in[3];   // (1,) f32
    float* out = (float*)d_out;                    // (1024,) f32

    qsim_kernel<<<out_size / 2, TPB, 0, stream>>>(state, params, head_w, head_b, out);
}

// Round 15
// 127.523 us; speedup vs baseline: 1.0280x; 1.0047x over previous
//
#include <hip/hip_runtime.h>
#include <utility>

#define NW 14
#define NL 3
#define DIM 16384            // 2^14
#define NG  (NL * NW)        // 42 fused RY*RX gates
#define TPB 1024
#define NPH3 11              // 10 phases of 4 gates + 1 phase of 2

typedef float v2f __attribute__((ext_vector_type(2)));

struct S3 {
    int ok = 1;
    unsigned Lane[NPH3][6] = {};   // lane dirs (tid bits 0..5) per phase
    unsigned Reg[NPH3][4]  = {};   // register/slot dirs per phase
    unsigned Vw[4]         = {};   // global wave dirs (tid bits 6..9)
    unsigned WT[NPH3][6]   = {};   // write consts: coords of lane dirs in NEXT frame
    unsigned WS[NPH3][16]  = {};   // write consts: coords of slot XORs in NEXT frame
    unsigned pv[NPH3][4]   = {};   // runtime sign: 10-bit tid parity mask per gate
    unsigned cp[NPH3][4]   = {};   // compile-time per-slot role bits per gate
    unsigned ST[10] = {}, STK[4] = {}, STJ[4] = {};   // staging coords (phase-0 frame)
    unsigned pz[NW] = {}, nib[NW] = {};               // measurement maps
};

// ---- cheap incremental echelon (no coords) ----
struct Bas14 { unsigned piv[14] = {}; int n = 0; };
constexpr bool binsert(Bas14& B, unsigned v) {
    unsigned x = v;
    for (int bit = 13; bit >= 0; --bit) {
        if (!((x >> bit) & 1u)) continue;
        if (B.piv[bit]) x ^= B.piv[bit];
        else { B.piv[bit] = x; ++B.n; return true; }
    }
    return false;
}

// ---- echelon with coordinate tracking: built ONCE per basis, cheap solves ----
struct Ech { unsigned pv14[14] = {}; unsigned pc14[14] = {}; int ok = 1; };
constexpr Ech mkech(const unsigned bas[14]) {
    Ech E{};
    for (int b = 0; b < 14; ++b) {
        unsigned x = bas[b], c = 1u << b;
        for (int bit = 13; bit >= 0; --bit) {
            if (!((x >> bit) & 1u)) continue;
            if (E.pv14[bit]) { x ^= E.pv14[bit]; c ^= E.pc14[bit]; }
            else { E.pv14[bit] = x; E.pc14[bit] = c; x = 0; break; }
        }
        if (x) E.ok = 0;
    }
    return E;
}
constexpr unsigned coordsE(const Ech& E, unsigned v, int& ok) {
    unsigned x = v, c = 0;
    for (int bit = 13; bit >= 0; --bit) {
        if ((x >> bit) & 1u) {
            if (!E.pv14[bit]) { ok = 0; return 0; }
            x ^= E.pv14[bit]; c ^= E.pc14[bit];
        }
    }
    return c;
}

constexpr S3 build3(int vskip) {
    S3 S{};
    unsigned mk[NG] = {}, vmg[NG] = {}, zm[NW] = {};
    {
        unsigned A[NW] = {};
        for (int w = 0; w < NW; ++w) A[w] = 1u << (NW - 1 - w);
        int g = 0;
        for (int l = 0; l < NL; ++l) {
            unsigned rows[NW] = {};
            for (int u = 0; u < NW; ++u) rows[u] = A[u] | (1u << (NW + u));
            for (int col = 0; col < NW; ++col) {
                int piv = col;
                while (piv < NW && !((rows[piv] >> col) & 1u)) ++piv;
                if (piv >= NW) { S.ok = 0; continue; }
                unsigned tmp = rows[col]; rows[col] = rows[piv]; rows[piv] = tmp;
                for (int r = 0; r < NW; ++r)
                    if (r != col && ((rows[r] >> col) & 1u)) rows[r] ^= rows[col];
            }
            for (int w = 0; w < NW; ++w) {
                unsigned m = 0;
                for (int r = 0; r < NW; ++r) m |= ((rows[r] >> (NW + w)) & 1u) << r;
                mk[g] = m; vmg[g] = A[w]; ++g;
            }
            for (int w = 0; w < NW - 1; ++w) A[w + 1] ^= A[w];  // virtual CNOT chain
            A[0] ^= A[NW - 1];
        }
        for (int w = 0; w < NW; ++w) zm[w] = A[w];
    }
    for (int p = 0; p < NPH3; ++p) {
        int J = (p < 10) ? 4 : 2;
        for (int q = 0; q < J; ++q) S.Reg[p][q] = mk[4 * p + q];
    }
    // global wave dirs: random 4-dim subspace independent of every group span
    {
        Bas14 gb[6] = {};
        for (int g = 0; g < 6; ++g) {
            int nm = (g < 5) ? 8 : 2;
            for (int i = 0; i < nm; ++i) binsert(gb[g], mk[8 * g + i]);
        }
        int found = 0, skipped = 0;
        for (unsigned seed = 1; seed < 512u && !found; ++seed) {
            unsigned cand[4] = {};
            for (int i = 0; i < 4; ++i) {
                unsigned h = (seed * 2654435761u) ^ ((unsigned)(i + 1) * 0x9E3779B9u);
                h ^= h >> 15; h *= 2246822519u; h ^= h >> 13; h *= 3266489917u; h ^= h >> 16;
                cand[i] = h & 0x3FFFu;
            }
            Bas14 cb{};
            bool good = binsert(cb, cand[0]) && binsert(cb, cand[1])
                     && binsert(cb, cand[2]) && binsert(cb, cand[3]);
            for (int g = 0; g < 6 && good; ++g) {
                Bas14 t = gb[g];
                for (int i = 0; i < 4 && good; ++i)
                    if (!binsert(t, cand[i])) good = false;
            }
            if (good) {
                if (skipped < vskip) { ++skipped; continue; }
                for (int i = 0; i < 4; ++i) S.Vw[i] = cand[i];
                found = 1;
            }
        }
        if (!found) S.ok = 0;
    }
    // per group: fillers and raw lane dirs (incremental echelon)
    for (int g = 0; g < 6; ++g) {
        int nm = (g < 5) ? 8 : 2;
        Bas14 B{};
        for (int i = 0; i < 4; ++i) binsert(B, S.Vw[i]);
        for (int i = 0; i < nm; ++i) binsert(B, mk[8 * g + i]);
        unsigned fill[12] = {}; int nf = 0;
        for (int b = 0; b < 14 && B.n < 14; ++b)
            if (binsert(B, 1u << b)) fill[nf++] = 1u << b;
        if (B.n != 14) S.ok = 0;
        if (g < 5) {
            int pA = 2 * g, pB = 2 * g + 1;
            for (int b = 0; b < 4; ++b) { S.Lane[pA][b] = S.Reg[pB][b]; S.Lane[pB][b] = S.Reg[pA][b]; }
            S.Lane[pA][4] = fill[0]; S.Lane[pA][5] = fill[1];
            S.Lane[pB][4] = fill[0]; S.Lane[pB][5] = fill[1];
        } else {
            S.Reg[10][2] = fill[0]; S.Reg[10][3] = fill[1];
            for (int b = 0; b < 6; ++b) S.Lane[10][b] = fill[2 + b];
        }
    }
    // transitions in reverse (echelon built once per transition)
    for (int t = NPH3 - 2; t >= 0; --t) {
        unsigned bas[14] = {};
        for (int b = 0; b < 6; ++b) bas[b] = S.Lane[t + 1][b];
        for (int q = 0; q < 4; ++q) bas[6 + q] = S.Reg[t + 1][q];
        for (int j = 0; j < 4; ++j) bas[10 + j] = S.Vw[j];
        Ech E = mkech(bas);
        if (!E.ok) S.ok = 0;
        unsigned rb[4] = {}; int rn = 0;
        for (int b = 0; b < 6; ++b) {
            int bestcs = 0, bestg = -1; unsigned bestr = 0;
            for (int cs = 0; cs < 16; ++cs) {
                unsigned c = 0;
                for (int q = 0; q < 4; ++q) if ((cs >> q) & 1) c ^= S.Reg[t][q];
                int ok2 = 1;
                unsigned r = coordsE(E, S.Lane[t][b] ^ c, ok2) & 15u;
                if (!ok2) continue;
                unsigned x = r;
                for (int i = 0; i < rn; ++i) {
                    int hb = 3; while (hb > 0 && !((rb[i] >> hb) & 1u)) --hb;
                    if ((x >> hb) & 1u) x ^= rb[i];
                }
                int gain = x ? 1 : 0;
                if (gain > bestg) { bestg = gain; bestcs = cs; bestr = r; }
                if (gain == 1) break;
            }
            unsigned c = 0;
            for (int q = 0; q < 4; ++q) if ((bestcs >> q) & 1) c ^= S.Reg[t][q];
            S.Lane[t][b] ^= c;
            unsigned x = bestr;
            for (int i = 0; i < rn; ++i) {
                int hb = 3; while (hb > 0 && !((rb[i] >> hb) & 1u)) --hb;
                if ((x >> hb) & 1u) x ^= rb[i];
            }
            if (x && rn < 4) rb[rn++] = x;
        }
        int okc = 1;
        for (int b = 0; b < 6; ++b) S.WT[t][b] = coordsE(E, S.Lane[t][b], okc);
        for (int s = 0; s < 16; ++s) {
            unsigned v = 0;
            for (int q = 0; q < 4; ++q) if ((s >> q) & 1) v ^= S.Reg[t][q];
            S.WS[t][s] = coordsE(E, v, okc);
        }
        if (!okc) S.ok = 0;
        // intra-group (even t) transitions must be wave-local: no Vw components.
        if ((t & 1) == 0) {
            for (int b = 0; b < 6; ++b) if (S.WT[t][b] >> 10) S.ok = 0;
            for (int s = 0; s < 16; ++s) if (S.WS[t][s] >> 10) S.ok = 0;
        }
        // verify: reader-amp(writer-idx) == writer-amp on basis inputs
        for (int ub = 0; ub < 10; ++ub) {
            unsigned wamp = (ub < 6) ? S.Lane[t][ub] : S.Vw[ub - 6];
            unsigned widx = (ub < 6) ? S.WT[t][ub] : (1u << (10 + ub - 6));
            unsigned ramp = 0;
            for (int b = 0; b < 6; ++b) if ((widx >> b) & 1u) ramp ^= S.Lane[t + 1][b];
            for (int q = 0; q < 4; ++q) if ((widx >> (6 + q)) & 1u) ramp ^= S.Reg[t + 1][q];
            for (int j = 0; j < 4; ++j) if ((widx >> (10 + j)) & 1u) ramp ^= S.Vw[j];
            if (ramp != wamp) S.ok = 0;
        }
        for (int q = 0; q < 4; ++q) {
            unsigned widx = S.WS[t][1u << q];
            unsigned ramp = 0;
            for (int b = 0; b < 6; ++b) if ((widx >> b) & 1u) ramp ^= S.Lane[t + 1][b];
            for (int qq = 0; qq < 4; ++qq) if ((widx >> (6 + qq)) & 1u) ramp ^= S.Reg[t + 1][qq];
            for (int j = 0; j < 4; ++j) if ((widx >> (10 + j)) & 1u) ramp ^= S.Vw[j];
            if (ramp != S.Reg[t][q]) S.ok = 0;
        }
    }
    // signs
    for (int p = 0; p < NPH3; ++p) {
        int J = (p < 10) ? 4 : 2;
        for (int q = 0; q < J; ++q) {
            unsigned vm = vmg[4 * p + q], pvm = 0;
            for (int b = 0; b < 6; ++b)
                if (__builtin_popcount(S.Lane[p][b] & vm) & 1) pvm |= 1u << b;
            for (int j = 0; j < 4; ++j)
                if (__builtin_popcount(S.Vw[j] & vm) & 1) pvm |= 1u << (6 + j);
            S.pv[p][q] = pvm;
            unsigned cpm = 0;
            for (int s = 0; s < 16; ++s) {
                unsigned v = 0;
                for (int q2 = 0; q2 < 4; ++q2) if ((s >> q2) & 1) v ^= S.Reg[p][q2];
                if (__builtin_popcount(v & vm) & 1) cpm |= 1u << s;
            }
            S.cp[p][q] = cpm;
        }
    }
    // staging coords + verification
    {
        unsigned bas[14] = {};
        for (int b = 0; b < 6; ++b) bas[b] = S.Lane[0][b];
        for (int q = 0; q < 4; ++q) bas[6 + q] = S.Reg[0][q];
        for (int j = 0; j < 4; ++j) bas[10 + j] = S.Vw[j];
        Ech E = mkech(bas);
        if (!E.ok) S.ok = 0;
        int okc = 1;
        for (int b = 0; b < 10; ++b) S.ST[b] = coordsE(E, 1u << (b + 2), okc);
        for (int k = 0; k < 4; ++k) S.STK[k] = coordsE(E, (unsigned)k << 12, okc);
        for (int j = 0; j < 4; ++j) S.STJ[j] = coordsE(E, (unsigned)j, okc);
        if (!okc) S.ok = 0;
        for (int ub = 0; ub < 18; ++ub) {
            unsigned amp = (ub < 10) ? (1u << (ub + 2))
                         : (ub < 14) ? ((unsigned)(ub - 10) << 12) : (unsigned)(ub - 14);
            unsigned widx = (ub < 10) ? S.ST[ub] : (ub < 14) ? S.STK[ub - 10] : S.STJ[ub - 14];
            unsigned ramp = 0;
            for (int b = 0; b < 6; ++b) if ((widx >> b) & 1u) ramp ^= S.Lane[0][b];
            for (int q = 0; q < 4; ++q) if ((widx >> (6 + q)) & 1u) ramp ^= S.Reg[0][q];
            for (int j = 0; j < 4; ++j) if ((widx >> (10 + j)) & 1u) ramp ^= S.Vw[j];
            if (ramp != amp) S.ok = 0;
        }
    }
    // measurement from phase-10 registers
    for (int w = 0; w < NW; ++w) {
        unsigned pzm = 0;
        for (int b = 0; b < 6; ++b)
            if (__builtin_popcount(S.Lane[10][b] & zm[w]) & 1) pzm |= 1u << b;
        for (int j = 0; j < 4; ++j)
            if (__builtin_popcount(S.Vw[j] & zm[w]) & 1) pzm |= 1u << (6 + j);
        S.pz[w] = pzm;
        unsigned nv = 0;
        for (int q = 0; q < 4; ++q)
            if (__builtin_popcount(S.Reg[q < 2 ? 10 : 10][q] & zm[w]) & 1) nv |= 1u << q;
        S.nib[w] = nv;
    }
    return S;
}
constexpr S3 pickBuild() {
    for (int v = 0; v < 4; ++v) {
        S3 s = build3(v);
        if (s.ok) return s;
    }
    S3 bad{}; bad.ok = 0; return bad;
}
constexpr S3 SC3 = pickBuild();
static_assert(SC3.ok == 1, "schedule build failed");

// ---------------- static_for ----------------
template<class F, unsigned... I>
__device__ __forceinline__ void static_for_impl(F&& f, std::integer_sequence<unsigned, I...>) {
    (f(std::integral_constant<unsigned, I>{}), ...);
}
template<unsigned N, class F>
__device__ __forceinline__ void static_for(F&& f) {
    static_for_impl(static_cast<F&&>(f), std::make_integer_sequence<unsigned, N>{});
}

// ---------------- packed complex mul/mac (verified r4..r14) ----------------
template<int NEGLO, int NEGHI>
__device__ __forceinline__ v2f cmul(v2f k, v2f x) {
    v2f y;
    if constexpr (!NEGLO)
        asm("v_pk_mul_f32 %0, %1, %2 op_sel:[0,0] op_sel_hi:[0,1]"
            : "=&v"(y) : "v"(k), "v"(x));
    else
        asm("v_pk_mul_f32 %0, %1, %2 op_sel:[0,0] op_sel_hi:[0,1] neg_lo:[1,0] neg_hi:[1,0]"
            : "=&v"(y) : "v"(k), "v"(x));
    if constexpr (!NEGHI)
        asm("v_pk_fma_f32 %0, %1, %2, %0 op_sel:[1,1,0] op_sel_hi:[1,0,1] neg_lo:[0,1,0]"
            : "+v"(y) : "v"(k), "v"(x));
    else
        asm("v_pk_fma_f32 %0, %1, %2, %0 op_sel:[1,1,0] op_sel_hi:[1,0,1] neg_lo:[1,1,0] neg_hi:[1,0,0]"
            : "+v"(y) : "v"(k), "v"(x));
    return y;
}
template<int NEGLO, int NEGHI>
__device__ __forceinline__ void cmac(v2f& y, v2f k, v2f x) {
    if constexpr (!NEGLO)
        asm("v_pk_fma_f32 %0, %1, %2, %0 op_sel:[0,0,0] op_sel_hi:[0,1,1]"
            : "+v"(y) : "v"(k), "v"(x));
    else
        asm("v_pk_fma_f32 %0, %1, %2, %0 op_sel:[0,0,0] op_sel_hi:[0,1,1] neg_lo:[1,0,0] neg_hi:[1,0,0]"
            : "+v"(y) : "v"(k), "v"(x));
    if constexpr (!NEGHI)
        asm("v_pk_fma_f32 %0, %1, %2, %0 op_sel:[1,1,0] op_sel_hi:[1,0,1] neg_lo:[0,1,0]"
            : "+v"(y) : "v"(k), "v"(x));
    else
        asm("v_pk_fma_f32 %0, %1, %2, %0 op_sel:[1,1,0] op_sel_hi:[1,0,1] neg_lo:[1,1,0] neg_hi:[1,0,0]"
            : "+v"(y) : "v"(k), "v"(x));
}
template<bool CS> __device__ __forceinline__ v2f  cmulA(v2f k, v2f x) { return cmul<0, CS ? 1 : 0>(k, x); }
template<bool CS> __device__ __forceinline__ void cmacB(v2f& y, v2f k, v2f x) { cmac<CS ? 1 : 0, 0>(y, k, x); }

// ---------------- gate sub-block [Q0, Q1) of phase P (registers only) ----------------
template<int P, int Q0, int Q1>
__device__ __forceinline__ void gates(v2f* x, const float4* __restrict__ umat, unsigned tid)
{
    static_for<Q1 - Q0>([&](auto Qc) {
        constexpr int q = Q0 + (int)decltype(Qc)::value;
        if constexpr (q < ((P < 10) ? 4 : 2)) {
            constexpr unsigned cp  = SC3.cp[P][q];
            constexpr unsigned pvm = SC3.pv[P][q];
            const float4 u = umat[4 * P + q];
            const unsigned sm = ((unsigned)__popc(tid & pvm)) << 31;
            v2f A, B;  // A = (ar, ai^s), B = (br^s, bi)
            A.x = u.x; A.y = __uint_as_float(__float_as_uint(u.y) ^ sm);
            B.x = __uint_as_float(__float_as_uint(u.z) ^ sm); B.y = u.w;
            static_for<8>([&](auto Pp) {
                constexpr unsigned pp   = decltype(Pp)::value;
                constexpr unsigned lowm = (1u << q) - 1u;
                constexpr unsigned s0   = ((pp & ~lowm) << 1) | (pp & lowm);
                constexpr unsigned s1   = s0 | (1u << q);
                constexpr bool c0 = (cp >> s0) & 1u;
                constexpr bool c1 = (cp >> s1) & 1u;
                const v2f x0 = x[s0], x1 = x[s1];
                v2f y0 = cmulA<c0>(A, x0); cmacB<c0>(y0, B, x1);
                v2f y1 = cmulA<c1>(A, x1); cmacB<c1>(y1, B, x0);
                x[s0] = y0; x[s1] = y1;
            });
        }
    });
}

// contiguous conflict-free reads: one base + immediate offsets
__device__ __forceinline__ void rdall(v2f* x, const char* psiB, unsigned rbase) {
    static_for<16>([&](auto Sc) {
        constexpr int s = (int)decltype(Sc)::value;
        x[s] = *(const v2f*)(psiB + rbase + (s << 9));
    });
}

// write phase-P output into frame P+1 (write base precomputed in prologue)
template<int P>
__device__ __forceinline__ void wrt(char* psiB, unsigned wib, const v2f* x) {
    static_for<16>([&](auto Sc) {
        constexpr int s = (int)decltype(Sc)::value;
        constexpr unsigned off = SC3.WS[P][s] << 3;
        *(v2f*)(psiB + (wib ^ off)) = x[s];
    });
}

// stage one row into the phase-0 frame from 4 prefetched float4s (imag = 0)
__device__ __forceinline__ void stageWreg(char* psiB, const float4* v, unsigned sidx) {
    static_for<4>([&](auto Kc) {
        constexpr int k = (int)decltype(Kc)::value;
        const unsigned bi = sidx ^ SC3.STK[k];
        *(v2f*)(psiB + ((bi ^ SC3.STJ[0]) << 3)) = (v2f){ v[k].x, 0.f };
        *(v2f*)(psiB + ((bi ^ SC3.STJ[1]) << 3)) = (v2f){ v[k].y, 0.f };
        *(v2f*)(psiB + ((bi ^ SC3.STJ[2]) << 3)) = (v2f){ v[k].z, 0.f };
        *(v2f*)(psiB + ((bi ^ SC3.STJ[3]) << 3)) = (v2f){ v[k].w, 0.f };
    });
}

__global__ __launch_bounds__(TPB, 4) void qsim_kernel(
    const float* __restrict__ state,
    const float* __restrict__ params,
    const float* __restrict__ head_w,
    const float* __restrict__ head_b,
    float* __restrict__ out)
{
    __shared__ v2f    psi[DIM];          // 128 KB: one full frame, shared A/B alternately
    __shared__ float4 umat[NG];
    __shared__ float  red[2 * (TPB / 64)];
    char* psiB = (char*)psi;
    const unsigned tid = threadIdx.x;

    // Fused U = RY(t2)*RX(t1) = [[a,b],[-conj(b),conj(a)]]; a=(c1c2,s1s2), b=(-s2c1,-c2s1)
    if (tid < NG) {
        float t1 = 0.5f * params[2 * tid + 0];
        float t2 = 0.5f * params[2 * tid + 1];
        float s1, c1, s2, c2;
        sincosf(t1, &s1, &c1);
        sincosf(t2, &s2, &c2);
        umat[tid] = make_float4(c1 * c2, s1 * s2, -s2 * c1, -c2 * s1);
    }

    const float4* st4A = reinterpret_cast<const float4*>(state + (size_t)(2 * blockIdx.x) * DIM);
    const float4* st4B = st4A + DIM / 4;

    unsigned sidx = 0;
    static_for<10>([&](auto Bc) {
        constexpr int b = (int)decltype(Bc)::value;
        sidx ^= SC3.ST[b] & (unsigned)(-(int)((tid >> b) & 1u));
    });
    // frame layout: byte = [wave(tid6..9) <<13 | slot <<9 | lane(tid0..5) <<3]
    const unsigned rbase = ((tid >> 6) << 13) | ((tid & 63u) << 3);

    // precompute all 10 transition write bases (constexpr-indexed -> VGPRs)
    unsigned wib[10];
    static_for<10>([&](auto Pc) {
        constexpr int P = (int)decltype(Pc)::value;
        unsigned wi = ((tid >> 6) & 15u) << 10;
        static_for<6>([&](auto Bc) {
            constexpr int b = (int)decltype(Bc)::value;
            constexpr unsigned m = SC3.WT[P][b];
            wi ^= m & (unsigned)(-(int)((tid >> b) & 1u));
        });
        wib[P] = wi << 3;
    });

    v2f xA[16], xB[16];

    // ---- prologue: load+stage A; prefetch B early (HBM latency hides under A)
    float4 vA[4], vB[4];
    static_for<4>([&](auto Kc) {
        constexpr int k = (int)decltype(Kc)::value;
        vA[k] = st4A[tid + k * TPB];
        vB[k] = st4B[tid + k * TPB];
    });
    stageWreg(psiB, vA, sidx);
    __syncthreads();
    rdall(xA, psiB, rbase);
    __syncthreads();
    stageWreg(psiB, vB, sidx);     // B staging writes overlap A's phase-0 gates
    gates<0, 0, 4>(xA, umat, tid);
    __syncthreads();
    rdall(xB, psiB, rbase);
    __syncthreads();

    // ---- dual-element pipeline.
    // Even P (intra-group): ALL LDS traffic is wave-local (build-verified) -> no barriers.
    // Odd P (cross-group): barrier-fenced, gates split 2+2 around bursts.
    static_for<10>([&](auto Pc) {
        constexpr int P = (int)decltype(Pc)::value;
        if constexpr ((P & 1) == 0) {
            wrt<P>(psiB, wib[P], xA);           // own region (wave-local)
            gates<P, 0, 4>(xB, umat, tid);
            rdall(xA, psiB, rbase);             // own region; in-wave DS order
            wrt<P>(psiB, wib[P], xB);
            gates<P + 1, 0, 2>(xA, umat, tid);
            rdall(xB, psiB, rbase);
            gates<P + 1, 2, 4>(xA, umat, tid);
        } else {
            __syncthreads();                    // all waves' local reads done
            wrt<P>(psiB, wib[P], xA);           // cross-region
            gates<P, 0, 2>(xB, umat, tid);
            __syncthreads();
            rdall(xA, psiB, rbase);
            gates<P, 2, 4>(xB, umat, tid);
            __syncthreads();
            wrt<P>(psiB, wib[P], xB);
            gates<P + 1, 0, 2>(xA, umat, tid);
            __syncthreads();
            rdall(xB, psiB, rbase);
            gates<P + 1, 2, 4>(xA, umat, tid);
        }
    });
    gates<10, 0, 4>(xB, umat, tid);

    // ---- measurement from registers (coefficients shared by A and B)
    float e[NW];
    static_for<NW>([&](auto Wc) {
        constexpr int w = (int)decltype(Wc)::value;
        constexpr unsigned pzw = SC3.pz[w];
        float hw = head_w[w];
        e[w] = (__popc(tid & pzw) & 1) ? -hw : hw;
    });
    float c[16];
    static_for<16>([&](auto Mc) { c[decltype(Mc)::value] = 0.f; });
    static_for<NW>([&](auto Wc) {
        constexpr int w = (int)decltype(Wc)::value;
        c[SC3.nib[w]] += e[w];
    });
    static_for<4>([&](auto Bc) {
        constexpr unsigned B = 1u << decltype(Bc)::value;
        static_for<16>([&](auto Kc) {
            constexpr unsigned k = decltype(Kc)::value;
            if constexpr (!(k & B)) {
                float a = c[k], b = c[k | B];
                c[k] = a + b; c[k | B] = a - b;
            }
        });
    });
    float accA = 0.f, accB = 0.f;
    static_for<16>([&](auto Sc) {
        constexpr int s = (int)decltype(Sc)::value;
        accA += (xA[s].x * xA[s].x + xA[s].y * xA[s].y) * c[s];
        accB += (xB[s].x * xB[s].x + xB[s].y * xB[s].y) * c[s];
    });

#pragma unroll
    for (int off = 32; off > 0; off >>= 1) {
        accA += __shfl_down(accA, off, 64);
        accB += __shfl_down(accB, off, 64);
    }
    const unsigned lane = tid & 63, wv = tid >> 6;
    if (lane == 0) { red[wv] = accA; red[(TPB / 64) + wv] = accB; }
    __syncthreads();
    if (tid == 0) {
        float tA = 0.f, tB = 0.f;
#pragma unroll
        for (int i = 0; i < TPB / 64; ++i) { tA += red[i]; tB += red[(TPB / 64) + i]; }
        out[2 * blockIdx.x + 0] = tA + head_b[0];
        out[2 * blockIdx.x + 1] = tB + head_b[0];
    }
}

extern "C" void kernel_launch(void* const* d_in, const int* in_sizes, int n_in,
                              void* d_out, int out_size, void* d_ws, size_t ws_size,
                              hipStream_t stream) {
    const float* state  = (const float*)d_in[0];   // (1024, 16384) f32
    const float* params = (const float*)d_in[1];   // (3, 14, 2) f32
    const float* head_w = (const float*)d_in[2];   // (1, 14) f32
    const float* head_b = (const float*)d_in[3];   // (1,) f32
    float* out = (float*)d_out;                    // (1024,) f32

    qsim_kernel<<<out_size / 2, TPB, 0, stream>>>(state, params, head_w, head_b, out);
}

// Round 16
// 127.160 us; speedup vs baseline: 1.0310x; 1.0029x over previous
//
#include <hip/hip_runtime.h>
#include <utility>

#define NW 14
#define NL 3
#define DIM 16384            // 2^14
#define NG  (NL * NW)        // 42 fused RY*RX gates
#define TPB 1024
#define NPH3 11              // 10 phases of 4 gates + 1 phase of 2

typedef float v2f __attribute__((ext_vector_type(2)));

struct S3 {
    int ok = 1;
    unsigned Lane[NPH3][6] = {};   // lane dirs (tid bits 0..5) per phase
    unsigned Reg[NPH3][4]  = {};   // register/slot dirs per phase
    unsigned Vw[4]         = {};   // global wave dirs (tid bits 6..9)
    unsigned WT[NPH3][6]   = {};   // write consts: coords of lane dirs in NEXT frame
    unsigned WS[NPH3][16]  = {};   // write consts: coords of slot XORs in NEXT frame
    unsigned pv[NPH3][4]   = {};   // runtime sign: 10-bit tid parity mask per gate
    unsigned cp[NPH3][4]   = {};   // compile-time per-slot role bits per gate
    unsigned ST[10] = {}, STK[4] = {}, STJ[4] = {};   // staging coords (phase-0 frame)
    unsigned pz[NW] = {}, nib[NW] = {};               // measurement maps
};

// ---- cheap incremental echelon (no coords) ----
struct Bas14 { unsigned piv[14] = {}; int n = 0; };
constexpr bool binsert(Bas14& B, unsigned v) {
    unsigned x = v;
    for (int bit = 13; bit >= 0; --bit) {
        if (!((x >> bit) & 1u)) continue;
        if (B.piv[bit]) x ^= B.piv[bit];
        else { B.piv[bit] = x; ++B.n; return true; }
    }
    return false;
}

// ---- echelon with coordinate tracking: built ONCE per basis, cheap solves ----
struct Ech { unsigned pv14[14] = {}; unsigned pc14[14] = {}; int ok = 1; };
constexpr Ech mkech(const unsigned bas[14]) {
    Ech E{};
    for (int b = 0; b < 14; ++b) {
        unsigned x = bas[b], c = 1u << b;
        for (int bit = 13; bit >= 0; --bit) {
            if (!((x >> bit) & 1u)) continue;
            if (E.pv14[bit]) { x ^= E.pv14[bit]; c ^= E.pc14[bit]; }
            else { E.pv14[bit] = x; E.pc14[bit] = c; x = 0; break; }
        }
        if (x) E.ok = 0;
    }
    return E;
}
constexpr unsigned coordsE(const Ech& E, unsigned v, int& ok) {
    unsigned x = v, c = 0;
    for (int bit = 13; bit >= 0; --bit) {
        if ((x >> bit) & 1u) {
            if (!E.pv14[bit]) { ok = 0; return 0; }
            x ^= E.pv14[bit]; c ^= E.pc14[bit];
        }
    }
    return c;
}

constexpr S3 build3(int vskip) {
    S3 S{};
    unsigned mk[NG] = {}, vmg[NG] = {}, zm[NW] = {};
    {
        unsigned A[NW] = {};
        for (int w = 0; w < NW; ++w) A[w] = 1u << (NW - 1 - w);
        int g = 0;
        for (int l = 0; l < NL; ++l) {
            unsigned rows[NW] = {};
            for (int u = 0; u < NW; ++u) rows[u] = A[u] | (1u << (NW + u));
            for (int col = 0; col < NW; ++col) {
                int piv = col;
                while (piv < NW && !((rows[piv] >> col) & 1u)) ++piv;
                if (piv >= NW) { S.ok = 0; continue; }
                unsigned tmp = rows[col]; rows[col] = rows[piv]; rows[piv] = tmp;
                for (int r = 0; r < NW; ++r)
                    if (r != col && ((rows[r] >> col) & 1u)) rows[r] ^= rows[col];
            }
            for (int w = 0; w < NW; ++w) {
                unsigned m = 0;
                for (int r = 0; r < NW; ++r) m |= ((rows[r] >> (NW + w)) & 1u) << r;
                mk[g] = m; vmg[g] = A[w]; ++g;
            }
            for (int w = 0; w < NW - 1; ++w) A[w + 1] ^= A[w];  // virtual CNOT chain
            A[0] ^= A[NW - 1];
        }
        for (int w = 0; w < NW; ++w) zm[w] = A[w];
    }
    for (int p = 0; p < NPH3; ++p) {
        int J = (p < 10) ? 4 : 2;
        for (int q = 0; q < J; ++q) S.Reg[p][q] = mk[4 * p + q];
    }
    // global wave dirs: random 4-dim subspace independent of every group span
    {
        Bas14 gb[6] = {};
        for (int g = 0; g < 6; ++g) {
            int nm = (g < 5) ? 8 : 2;
            for (int i = 0; i < nm; ++i) binsert(gb[g], mk[8 * g + i]);
        }
        int found = 0, skipped = 0;
        for (unsigned seed = 1; seed < 512u && !found; ++seed) {
            unsigned cand[4] = {};
            for (int i = 0; i < 4; ++i) {
                unsigned h = (seed * 2654435761u) ^ ((unsigned)(i + 1) * 0x9E3779B9u);
                h ^= h >> 15; h *= 2246822519u; h ^= h >> 13; h *= 3266489917u; h ^= h >> 16;
                cand[i] = h & 0x3FFFu;
            }
            Bas14 cb{};
            bool good = binsert(cb, cand[0]) && binsert(cb, cand[1])
                     && binsert(cb, cand[2]) && binsert(cb, cand[3]);
            for (int g = 0; g < 6 && good; ++g) {
                Bas14 t = gb[g];
                for (int i = 0; i < 4 && good; ++i)
                    if (!binsert(t, cand[i])) good = false;
            }
            if (good) {
                if (skipped < vskip) { ++skipped; continue; }
                for (int i = 0; i < 4; ++i) S.Vw[i] = cand[i];
                found = 1;
            }
        }
        if (!found) S.ok = 0;
    }
    // per group: fillers and raw lane dirs (incremental echelon)
    for (int g = 0; g < 6; ++g) {
        int nm = (g < 5) ? 8 : 2;
        Bas14 B{};
        for (int i = 0; i < 4; ++i) binsert(B, S.Vw[i]);
        for (int i = 0; i < nm; ++i) binsert(B, mk[8 * g + i]);
        unsigned fill[12] = {}; int nf = 0;
        for (int b = 0; b < 14 && B.n < 14; ++b)
            if (binsert(B, 1u << b)) fill[nf++] = 1u << b;
        if (B.n != 14) S.ok = 0;
        if (g < 5) {
            int pA = 2 * g, pB = 2 * g + 1;
            for (int b = 0; b < 4; ++b) { S.Lane[pA][b] = S.Reg[pB][b]; S.Lane[pB][b] = S.Reg[pA][b]; }
            S.Lane[pA][4] = fill[0]; S.Lane[pA][5] = fill[1];
            S.Lane[pB][4] = fill[0]; S.Lane[pB][5] = fill[1];
        } else {
            S.Reg[10][2] = fill[0]; S.Reg[10][3] = fill[1];
            for (int b = 0; b < 6; ++b) S.Lane[10][b] = fill[2 + b];
        }
    }
    // transitions in reverse (echelon built once per transition)
    for (int t = NPH3 - 2; t >= 0; --t) {
        unsigned bas[14] = {};
        for (int b = 0; b < 6; ++b) bas[b] = S.Lane[t + 1][b];
        for (int q = 0; q < 4; ++q) bas[6 + q] = S.Reg[t + 1][q];
        for (int j = 0; j < 4; ++j) bas[10 + j] = S.Vw[j];
        Ech E = mkech(bas);
        if (!E.ok) S.ok = 0;
        unsigned rb[4] = {}; int rn = 0;
        for (int b = 0; b < 6; ++b) {
            int bestcs = 0, bestg = -1; unsigned bestr = 0;
            for (int cs = 0; cs < 16; ++cs) {
                unsigned c = 0;
                for (int q = 0; q < 4; ++q) if ((cs >> q) & 1) c ^= S.Reg[t][q];
                int ok2 = 1;
                unsigned r = coordsE(E, S.Lane[t][b] ^ c, ok2) & 15u;
                if (!ok2) continue;
                unsigned x = r;
                for (int i = 0; i < rn; ++i) {
                    int hb = 3; while (hb > 0 && !((rb[i] >> hb) & 1u)) --hb;
                    if ((x >> hb) & 1u) x ^= rb[i];
                }
                int gain = x ? 1 : 0;
                if (gain > bestg) { bestg = gain; bestcs = cs; bestr = r; }
                if (gain == 1) break;
            }
            unsigned c = 0;
            for (int q = 0; q < 4; ++q) if ((bestcs >> q) & 1) c ^= S.Reg[t][q];
            S.Lane[t][b] ^= c;
            unsigned x = bestr;
            for (int i = 0; i < rn; ++i) {
                int hb = 3; while (hb > 0 && !((rb[i] >> hb) & 1u)) --hb;
                if ((x >> hb) & 1u) x ^= rb[i];
            }
            if (x && rn < 4) rb[rn++] = x;
        }
        int okc = 1;
        for (int b = 0; b < 6; ++b) S.WT[t][b] = coordsE(E, S.Lane[t][b], okc);
        for (int s = 0; s < 16; ++s) {
            unsigned v = 0;
            for (int q = 0; q < 4; ++q) if ((s >> q) & 1) v ^= S.Reg[t][q];
            S.WS[t][s] = coordsE(E, v, okc);
        }
        if (!okc) S.ok = 0;
        // intra-group (even t) transitions must be wave-local: no Vw components.
        if ((t & 1) == 0) {
            for (int b = 0; b < 6; ++b) if (S.WT[t][b] >> 10) S.ok = 0;
            for (int s = 0; s < 16; ++s) if (S.WS[t][s] >> 10) S.ok = 0;
        }
        // verify: reader-amp(writer-idx) == writer-amp on basis inputs
        for (int ub = 0; ub < 10; ++ub) {
            unsigned wamp = (ub < 6) ? S.Lane[t][ub] : S.Vw[ub - 6];
            unsigned widx = (ub < 6) ? S.WT[t][ub] : (1u << (10 + ub - 6));
            unsigned ramp = 0;
            for (int b = 0; b < 6; ++b) if ((widx >> b) & 1u) ramp ^= S.Lane[t + 1][b];
            for (int q = 0; q < 4; ++q) if ((widx >> (6 + q)) & 1u) ramp ^= S.Reg[t + 1][q];
            for (int j = 0; j < 4; ++j) if ((widx >> (10 + j)) & 1u) ramp ^= S.Vw[j];
            if (ramp != wamp) S.ok = 0;
        }
        for (int q = 0; q < 4; ++q) {
            unsigned widx = S.WS[t][1u << q];
            unsigned ramp = 0;
            for (int b = 0; b < 6; ++b) if ((widx >> b) & 1u) ramp ^= S.Lane[t + 1][b];
            for (int qq = 0; qq < 4; ++qq) if ((widx >> (6 + qq)) & 1u) ramp ^= S.Reg[t + 1][qq];
            for (int j = 0; j < 4; ++j) if ((widx >> (10 + j)) & 1u) ramp ^= S.Vw[j];
            if (ramp != S.Reg[t][q]) S.ok = 0;
        }
    }
    // signs
    for (int p = 0; p < NPH3; ++p) {
        int J = (p < 10) ? 4 : 2;
        for (int q = 0; q < J; ++q) {
            unsigned vm = vmg[4 * p + q], pvm = 0;
            for (int b = 0; b < 6; ++b)
                if (__builtin_popcount(S.Lane[p][b] & vm) & 1) pvm |= 1u << b;
            for (int j = 0; j < 4; ++j)
                if (__builtin_popcount(S.Vw[j] & vm) & 1) pvm |= 1u << (6 + j);
            S.pv[p][q] = pvm;
            unsigned cpm = 0;
            for (int s = 0; s < 16; ++s) {
                unsigned v = 0;
                for (int q2 = 0; q2 < 4; ++q2) if ((s >> q2) & 1) v ^= S.Reg[p][q2];
                if (__builtin_popcount(v & vm) & 1) cpm |= 1u << s;
            }
            S.cp[p][q] = cpm;
        }
    }
    // staging coords + verification
    {
        unsigned bas[14] = {};
        for (int b = 0; b < 6; ++b) bas[b] = S.Lane[0][b];
        for (int q = 0; q < 4; ++q) bas[6 + q] = S.Reg[0][q];
        for (int j = 0; j < 4; ++j) bas[10 + j] = S.Vw[j];
        Ech E = mkech(bas);
        if (!E.ok) S.ok = 0;
        int okc = 1;
        for (int b = 0; b < 10; ++b) S.ST[b] = coordsE(E, 1u << (b + 2), okc);
        for (int k = 0; k < 4; ++k) S.STK[k] = coordsE(E, (unsigned)k << 12, okc);
        for (int j = 0; j < 4; ++j) S.STJ[j] = coordsE(E, (unsigned)j, okc);
        if (!okc) S.ok = 0;
        for (int ub = 0; ub < 18; ++ub) {
            unsigned amp = (ub < 10) ? (1u << (ub + 2))
                         : (ub < 14) ? ((unsigned)(ub - 10) << 12) : (unsigned)(ub - 14);
            unsigned widx = (ub < 10) ? S.ST[ub] : (ub < 14) ? S.STK[ub - 10] : S.STJ[ub - 14];
            unsigned ramp = 0;
            for (int b = 0; b < 6; ++b) if ((widx >> b) & 1u) ramp ^= S.Lane[0][b];
            for (int q = 0; q < 4; ++q) if ((widx >> (6 + q)) & 1u) ramp ^= S.Reg[0][q];
            for (int j = 0; j < 4; ++j) if ((widx >> (10 + j)) & 1u) ramp ^= S.Vw[j];
            if (ramp != amp) S.ok = 0;
        }
    }
    // measurement from phase-10 registers
    for (int w = 0; w < NW; ++w) {
        unsigned pzm = 0;
        for (int b = 0; b < 6; ++b)
            if (__builtin_popcount(S.Lane[10][b] & zm[w]) & 1) pzm |= 1u << b;
        for (int j = 0; j < 4; ++j)
            if (__builtin_popcount(S.Vw[j] & zm[w]) & 1) pzm |= 1u << (6 + j);
        S.pz[w] = pzm;
        unsigned nv = 0;
        for (int q = 0; q < 4; ++q)
            if (__builtin_popcount(S.Reg[10][q] & zm[w]) & 1) nv |= 1u << q;
        S.nib[w] = nv;
    }
    return S;
}
constexpr S3 pickBuild() {
    for (int v = 0; v < 4; ++v) {
        S3 s = build3(v);
        if (s.ok) return s;
    }
    S3 bad{}; bad.ok = 0; return bad;
}
constexpr S3 SC3 = pickBuild();
static_assert(SC3.ok == 1, "schedule build failed");

// ---------------- static_for ----------------
template<class F, unsigned... I>
__device__ __forceinline__ void static_for_impl(F&& f, std::integer_sequence<unsigned, I...>) {
    (f(std::integral_constant<unsigned, I>{}), ...);
}
template<unsigned N, class F>
__device__ __forceinline__ void static_for(F&& f) {
    static_for_impl(static_cast<F&&>(f), std::make_integer_sequence<unsigned, N>{});
}

// ---------------- packed complex mul/mac (verified r4..r15) ----------------
template<int NEGLO, int NEGHI>
__device__ __forceinline__ v2f cmul(v2f k, v2f x) {
    v2f y;
    if constexpr (!NEGLO)
        asm("v_pk_mul_f32 %0, %1, %2 op_sel:[0,0] op_sel_hi:[0,1]"
            : "=&v"(y) : "v"(k), "v"(x));
    else
        asm("v_pk_mul_f32 %0, %1, %2 op_sel:[0,0] op_sel_hi:[0,1] neg_lo:[1,0] neg_hi:[1,0]"
            : "=&v"(y) : "v"(k), "v"(x));
    if constexpr (!NEGHI)
        asm("v_pk_fma_f32 %0, %1, %2, %0 op_sel:[1,1,0] op_sel_hi:[1,0,1] neg_lo:[0,1,0]"
            : "+v"(y) : "v"(k), "v"(x));
    else
        asm("v_pk_fma_f32 %0, %1, %2, %0 op_sel:[1,1,0] op_sel_hi:[1,0,1] neg_lo:[1,1,0] neg_hi:[1,0,0]"
            : "+v"(y) : "v"(k), "v"(x));
    return y;
}
template<int NEGLO, int NEGHI>
__device__ __forceinline__ void cmac(v2f& y, v2f k, v2f x) {
    if constexpr (!NEGLO)
        asm("v_pk_fma_f32 %0, %1, %2, %0 op_sel:[0,0,0] op_sel_hi:[0,1,1]"
            : "+v"(y) : "v"(k), "v"(x));
    else
        asm("v_pk_fma_f32 %0, %1, %2, %0 op_sel:[0,0,0] op_sel_hi:[0,1,1] neg_lo:[1,0,0] neg_hi:[1,0,0]"
            : "+v"(y) : "v"(k), "v"(x));
    if constexpr (!NEGHI)
        asm("v_pk_fma_f32 %0, %1, %2, %0 op_sel:[1,1,0] op_sel_hi:[1,0,1] neg_lo:[0,1,0]"
            : "+v"(y) : "v"(k), "v"(x));
    else
        asm("v_pk_fma_f32 %0, %1, %2, %0 op_sel:[1,1,0] op_sel_hi:[1,0,1] neg_lo:[1,1,0] neg_hi:[1,0,0]"
            : "+v"(y) : "v"(k), "v"(x));
}
template<bool CS> __device__ __forceinline__ v2f  cmulA(v2f k, v2f x) { return cmul<0, CS ? 1 : 0>(k, x); }
template<bool CS> __device__ __forceinline__ void cmacB(v2f& y, v2f k, v2f x) { cmac<CS ? 1 : 0, 0>(y, k, x); }

// ---------------- per-phase coefficient construction (shared by A and B) ----------------
template<int P>
__device__ __forceinline__ void mkAB(v2f* AB, const float4* __restrict__ umat, unsigned tid) {
    static_for<4>([&](auto Qc) {
        constexpr int q = (int)decltype(Qc)::value;
        if constexpr (q < ((P < 10) ? 4 : 2)) {
            constexpr unsigned pvm = SC3.pv[P][q];
            const float4 u = umat[4 * P + q];
            const unsigned sm = ((unsigned)__popc(tid & pvm)) << 31;
            v2f A, B;  // A = (ar, ai^s), B = (br^s, bi)
            A.x = u.x; A.y = __uint_as_float(__float_as_uint(u.y) ^ sm);
            B.x = __uint_as_float(__float_as_uint(u.z) ^ sm); B.y = u.w;
            AB[2 * q] = A; AB[2 * q + 1] = B;
        }
    });
}

// ---------------- gate sub-block [Q0, Q1) of phase P (registers only) ----------------
template<int P, int Q0, int Q1>
__device__ __forceinline__ void gates(v2f* x, const v2f* AB)
{
    static_for<Q1 - Q0>([&](auto Qc) {
        constexpr int q = Q0 + (int)decltype(Qc)::value;
        if constexpr (q < ((P < 10) ? 4 : 2)) {
            constexpr unsigned cp = SC3.cp[P][q];
            const v2f A = AB[2 * q], B = AB[2 * q + 1];
            static_for<8>([&](auto Pp) {
                constexpr unsigned pp   = decltype(Pp)::value;
                constexpr unsigned lowm = (1u << q) - 1u;
                constexpr unsigned s0   = ((pp & ~lowm) << 1) | (pp & lowm);
                constexpr unsigned s1   = s0 | (1u << q);
                constexpr bool c0 = (cp >> s0) & 1u;
                constexpr bool c1 = (cp >> s1) & 1u;
                const v2f x0 = x[s0], x1 = x[s1];
                v2f y0 = cmulA<c0>(A, x0); cmacB<c0>(y0, B, x1);
                v2f y1 = cmulA<c1>(A, x1); cmacB<c1>(y1, B, x0);
                x[s0] = y0; x[s1] = y1;
            });
        }
    });
}

// contiguous conflict-free reads: one base + immediate offsets
__device__ __forceinline__ void rdall(v2f* x, const char* psiB, unsigned rbase) {
    static_for<16>([&](auto Sc) {
        constexpr int s = (int)decltype(Sc)::value;
        x[s] = *(const v2f*)(psiB + rbase + (s << 9));
    });
}

// write phase-P output into frame P+1 (write base precomputed in prologue)
template<int P>
__device__ __forceinline__ void wrt(char* psiB, unsigned wib, const v2f* x) {
    static_for<16>([&](auto Sc) {
        constexpr int s = (int)decltype(Sc)::value;
        constexpr unsigned off = SC3.WS[P][s] << 3;
        *(v2f*)(psiB + (wib ^ off)) = x[s];
    });
}

// stage one row into the phase-0 frame from 4 prefetched float4s (imag = 0)
__device__ __forceinline__ void stageWreg(char* psiB, const float4* v, unsigned sidx) {
    static_for<4>([&](auto Kc) {
        constexpr int k = (int)decltype(Kc)::value;
        const unsigned bi = sidx ^ SC3.STK[k];
        *(v2f*)(psiB + ((bi ^ SC3.STJ[0]) << 3)) = (v2f){ v[k].x, 0.f };
        *(v2f*)(psiB + ((bi ^ SC3.STJ[1]) << 3)) = (v2f){ v[k].y, 0.f };
        *(v2f*)(psiB + ((bi ^ SC3.STJ[2]) << 3)) = (v2f){ v[k].z, 0.f };
        *(v2f*)(psiB + ((bi ^ SC3.STJ[3]) << 3)) = (v2f){ v[k].w, 0.f };
    });
}

__global__ __launch_bounds__(TPB, 4) void qsim_kernel(
    const float* __restrict__ state,
    const float* __restrict__ params,
    const float* __restrict__ head_w,
    const float* __restrict__ head_b,
    float* __restrict__ out)
{
    __shared__ v2f    psi[DIM];          // 128 KB: one full frame, shared A/B alternately
    __shared__ float4 umat[NG];
    __shared__ float  red[2 * (TPB / 64)];
    char* psiB = (char*)psi;
    const unsigned tid = threadIdx.x;

    // Fused U = RY(t2)*RX(t1) = [[a,b],[-conj(b),conj(a)]]; a=(c1c2,s1s2), b=(-s2c1,-c2s1)
    if (tid < NG) {
        float t1 = 0.5f * params[2 * tid + 0];
        float t2 = 0.5f * params[2 * tid + 1];
        float s1, c1, s2, c2;
        sincosf(t1, &s1, &c1);
        sincosf(t2, &s2, &c2);
        umat[tid] = make_float4(c1 * c2, s1 * s2, -s2 * c1, -c2 * s1);
    }

    const float4* st4A = reinterpret_cast<const float4*>(state + (size_t)(2 * blockIdx.x) * DIM);
    const float4* st4B = st4A + DIM / 4;

    unsigned sidx = 0;
    static_for<10>([&](auto Bc) {
        constexpr int b = (int)decltype(Bc)::value;
        sidx ^= SC3.ST[b] & (unsigned)(-(int)((tid >> b) & 1u));
    });
    // frame layout: byte = [wave(tid6..9) <<13 | slot <<9 | lane(tid0..5) <<3]
    const unsigned rbase = ((tid >> 6) << 13) | ((tid & 63u) << 3);

    // precompute all 10 transition write bases (constexpr-indexed -> VGPRs)
    unsigned wib[10];
    static_for<10>([&](auto Pc) {
        constexpr int P = (int)decltype(Pc)::value;
        unsigned wi = ((tid >> 6) & 15u) << 10;
        static_for<6>([&](auto Bc) {
            constexpr int b = (int)decltype(Bc)::value;
            constexpr unsigned m = SC3.WT[P][b];
            wi ^= m & (unsigned)(-(int)((tid >> b) & 1u));
        });
        wib[P] = wi << 3;
    });

    v2f xA[16], xB[16];
    v2f ABa[8], ABb[8];   // rolling coefficient cache: phase p -> (p&1 ? ABb : ABa)

    // ---- prologue: load+stage A; prefetch B early (HBM latency hides under A)
    float4 vA[4], vB[4];
    static_for<4>([&](auto Kc) {
        constexpr int k = (int)decltype(Kc)::value;
        vA[k] = st4A[tid + k * TPB];
        vB[k] = st4B[tid + k * TPB];
    });
    stageWreg(psiB, vA, sidx);
    __syncthreads();
    rdall(xA, psiB, rbase);
    __syncthreads();
    stageWreg(psiB, vB, sidx);     // B staging writes overlap A's phase-0 gates
    mkAB<0>(ABa, umat, tid);
    gates<0, 0, 4>(xA, ABa);
    __syncthreads();
    rdall(xB, psiB, rbase);
    __syncthreads();

    // ---- dual-element pipeline.
    // Even P (intra-group): ALL LDS traffic is wave-local (build-verified) -> no barriers.
    // Odd P (cross-group): barrier-fenced, gates split 2+2 around bursts.
    // Coefficients for each phase computed ONCE, shared by both elements.
    static_for<10>([&](auto Pc) {
        constexpr int P = (int)decltype(Pc)::value;
        v2f* const ABp = (P & 1) ? ABb : ABa;        // phase P coeffs (from prev iter)
        v2f* const ABn = (P & 1) ? ABa : ABb;        // phase P+1 coeffs (made now)
        mkAB<P + 1>(ABn, umat, tid);
        if constexpr ((P & 1) == 0) {
            wrt<P>(psiB, wib[P], xA);           // own region (wave-local)
            gates<P, 0, 4>(xB, ABp);
            rdall(xA, psiB, rbase);             // own region; in-wave DS order
            wrt<P>(psiB, wib[P], xB);
            gates<P + 1, 0, 2>(xA, ABn);
            rdall(xB, psiB, rbase);
            gates<P + 1, 2, 4>(xA, ABn);
        } else {
            __syncthreads();                    // all waves' local reads done
            wrt<P>(psiB, wib[P], xA);           // cross-region
            gates<P, 0, 2>(xB, ABp);
            __syncthreads();
            rdall(xA, psiB, rbase);
            gates<P, 2, 4>(xB, ABp);
            __syncthreads();
            wrt<P>(psiB, wib[P], xB);
            gates<P + 1, 0, 2>(xA, ABn);
            __syncthreads();
            rdall(xB, psiB, rbase);
            gates<P + 1, 2, 4>(xA, ABn);
        }
    });
    gates<10, 0, 4>(xB, ABa);   // phase 10 coeffs were made at P=9 into ABa (10&1==0)

    // ---- measurement from registers (coefficients shared by A and B)
    float e[NW];
    static_for<NW>([&](auto Wc) {
        constexpr int w = (int)decltype(Wc)::value;
        constexpr unsigned pzw = SC3.pz[w];
        float hw = head_w[w];
        e[w] = (__popc(tid & pzw) & 1) ? -hw : hw;
    });
    float c[16];
    static_for<16>([&](auto Mc) { c[decltype(Mc)::value] = 0.f; });
    static_for<NW>([&](auto Wc) {
        constexpr int w = (int)decltype(Wc)::value;
        c[SC3.nib[w]] += e[w];
    });
    static_for<4>([&](auto Bc) {
        constexpr unsigned B = 1u << decltype(Bc)::value;
        static_for<16>([&](auto Kc) {
            constexpr unsigned k = decltype(Kc)::value;
            if constexpr (!(k & B)) {
                float a = c[k], b = c[k | B];
                c[k] = a + b; c[k | B] = a - b;
            }
        });
    });
    float accA = 0.f, accB = 0.f;
    static_for<16>([&](auto Sc) {
        constexpr int s = (int)decltype(Sc)::value;
        accA += (xA[s].x * xA[s].x + xA[s].y * xA[s].y) * c[s];
        accB += (xB[s].x * xB[s].x + xB[s].y * xB[s].y) * c[s];
    });

#pragma unroll
    for (int off = 32; off > 0; off >>= 1) {
        accA += __shfl_down(accA, off, 64);
        accB += __shfl_down(accB, off, 64);
    }
    const unsigned lane = tid & 63, wv = tid >> 6;
    if (lane == 0) { red[wv] = accA; red[(TPB / 64) + wv] = accB; }
    __syncthreads();
    if (tid == 0) {
        float tA = 0.f, tB = 0.f;
#pragma unroll
        for (int i = 0; i < TPB / 64; ++i) { tA += red[i]; tB += red[(TPB / 64) + i]; }
        out[2 * blockIdx.x + 0] = tA + head_b[0];
        out[2 * blockIdx.x + 1] = tB + head_b[0];
    }
}

extern "C" void kernel_launch(void* const* d_in, const int* in_sizes, int n_in,
                              void* d_out, int out_size, void* d_ws, size_t ws_size,
                              hipStream_t stream) {
    const float* state  = (const float*)d_in[0];   // (1024, 16384) f32
    const float* params = (const float*)d_in[1];   // (3, 14, 2) f32
    const float* head_w = (const float*)d_in[2];   // (1, 14) f32
    const float* head_b = (const float*)d_in[3];   // (1,) f32
    float* out = (float*)d_out;                    // (1024,) f32

    qsim_kernel<<<out_size / 2, TPB, 0, stream>>>(state, params, head_w, head_b, out);
}